// Round 1
// baseline (1683.656 us; speedup 1.0000x reference)
//
#include <hip/hip_runtime.h>
#include <math.h>

#define HID 128
#define NG_GAUSS 50
#define TBL_P 4096
#define TBL_DMAX 12.8f
#define TBL_DT (TBL_DMAX / (float)TBL_P)
#define TBL_INV_DT ((float)TBL_P / TBL_DMAX)
#define PI_F 3.14159265358979323846f

__device__ __forceinline__ float ssp_f(float x) {
  // shifted softplus: stable softplus(x) - ln(2)
  return fmaxf(x, 0.f) + log1pf(expf(-fabsf(x))) - 0.69314718055994530942f;
}

// ---------------- edge precompute: d, C, table coords, degree histogram ----
__global__ __launch_bounds__(256) void k_edge_pre(
    const float* __restrict__ pos, const int* __restrict__ ei,
    int E, int4* __restrict__ epack, int* __restrict__ deg)
{
  int e = blockIdx.x * 256 + threadIdx.x;
  if (e >= E) return;
  int r = ei[e];
  int c = ei[E + e];
  float dx = pos[3*r+0] - pos[3*c+0];
  float dy = pos[3*r+1] - pos[3*c+1];
  float dz = pos[3*r+2] - pos[3*c+2];
  float d = sqrtf(dx*dx + dy*dy + dz*dz);
  float Cc = 0.5f * (cosf(d * (PI_F / 10.0f)) + 1.0f);
  float u = d * TBL_INV_DT;
  int i0 = (int)u;
  if (i0 > TBL_P - 2) i0 = TBL_P - 2;
  float frac = fminf(u - (float)i0, 1.0f);
  epack[e] = make_int4(r, i0, __float_as_int(frac), __float_as_int(Cc));
  atomicAdd(&deg[c], 1);
}

// ---------------- exclusive scan over degrees (single block) --------------
__global__ __launch_bounds__(1024) void k_scan(
    const int* __restrict__ deg, int* __restrict__ ptr, int N)
{
  __shared__ int s[1024];
  __shared__ int carry;
  int t = threadIdx.x;
  if (t == 0) carry = 0;
  __syncthreads();
  for (int base = 0; base < N; base += 1024) {
    int v = (base + t < N) ? deg[base + t] : 0;
    s[t] = v;
    __syncthreads();
    for (int off = 1; off < 1024; off <<= 1) {
      int x = (t >= off) ? s[t - off] : 0;
      __syncthreads();
      s[t] += x;
      __syncthreads();
    }
    int my = carry + s[t] - v;
    if (base + t < N) ptr[base + t] = my;
    __syncthreads();
    if (t == 1023) carry += s[1023];
    __syncthreads();
  }
  if (t == 0) ptr[N] = carry;
}

// ---------------- scatter edges into CSR order ----------------------------
__global__ __launch_bounds__(256) void k_csr_scatter(
    const int* __restrict__ col, const int4* __restrict__ epack,
    const int* __restrict__ ptr, int* __restrict__ cursor,
    int4* __restrict__ csr, int E)
{
  int e = blockIdx.x * 256 + threadIdx.x;
  if (e >= E) return;
  int c = col[e];
  int slot = ptr[c] + atomicAdd(&cursor[c], 1);
  csr[slot] = epack[e];
}

// ---------------- gaussian feature table [TBL_P][64] (zero-padded) --------
__global__ void k_ea_build(float* __restrict__ EA)
{
  int p = blockIdx.x;
  int g = threadIdx.x; // 64 threads
  float dp = p * TBL_DT;
  float v = 0.f;
  if (g < NG_GAUSS) {
    float step = 10.0f / 49.0f;
    float off = g * step;
    float coeff = -0.5f / (step * step);
    float t = dp - off;
    v = expf(coeff * t * t);
  }
  EA[p * 64 + g] = v;
}

// ---------------- h init: h = emb[z] --------------------------------------
__global__ __launch_bounds__(256) void k_h_init(
    const float4* __restrict__ emb4, const int* __restrict__ z,
    float4* __restrict__ h4, int N)
{
  int idx = blockIdx.x * 256 + threadIdx.x;
  if (idx >= N * 32) return;
  int n = idx >> 5, c = idx & 31;
  h4[idx] = emb4[z[n] * 32 + c];
}

// ---------------- generic 128-col GEMM: Y = act(X@W + b) [+ R] ------------
// X: [M, ldx] (use first K cols), W: [K,128], all fp32.
__global__ __launch_bounds__(256) void k_gemm(
    const float* __restrict__ X, int ldx,
    const float* __restrict__ W,
    const float* __restrict__ Bv,
    const float* __restrict__ R,
    float* __restrict__ Y,
    int M, int K, int act)
{
  __shared__ float Xt[128][36];   // [k][r], zero-padded for k>=K
  __shared__ float Ws[64][132];
  const int tid = threadIdx.x;
  const int m0 = blockIdx.x * 32;

  for (int idx = tid; idx < 32 * 128; idx += 256) {
    int r = idx >> 7;
    int k = idx & 127;
    int m = m0 + r;
    float v = 0.f;
    if (k < K && m < M) v = X[(size_t)m * ldx + k];
    Xt[k][r] = v;
  }

  float acc[4][4];
#pragma unroll
  for (int i = 0; i < 4; ++i)
#pragma unroll
    for (int j = 0; j < 4; ++j) acc[i][j] = 0.f;

  const int r0 = (tid >> 5) << 2;
  const int c0 = (tid & 31) << 2;

  for (int k0 = 0; k0 < K; k0 += 64) {
    __syncthreads();
    for (int idx = tid; idx < 64 * 128; idx += 256) {
      int kk = idx >> 7;
      int c = idx & 127;
      int k = k0 + kk;
      Ws[kk][c] = (k < K) ? W[(size_t)k * 128 + c] : 0.f;
    }
    __syncthreads();
#pragma unroll
    for (int kk = 0; kk < 64; ++kk) {
      const float4 xv = *(const float4*)&Xt[k0 + kk][r0];
      const float4 wv = *(const float4*)&Ws[kk][c0];
      acc[0][0] = fmaf(xv.x, wv.x, acc[0][0]);
      acc[0][1] = fmaf(xv.x, wv.y, acc[0][1]);
      acc[0][2] = fmaf(xv.x, wv.z, acc[0][2]);
      acc[0][3] = fmaf(xv.x, wv.w, acc[0][3]);
      acc[1][0] = fmaf(xv.y, wv.x, acc[1][0]);
      acc[1][1] = fmaf(xv.y, wv.y, acc[1][1]);
      acc[1][2] = fmaf(xv.y, wv.z, acc[1][2]);
      acc[1][3] = fmaf(xv.y, wv.w, acc[1][3]);
      acc[2][0] = fmaf(xv.z, wv.x, acc[2][0]);
      acc[2][1] = fmaf(xv.z, wv.y, acc[2][1]);
      acc[2][2] = fmaf(xv.z, wv.z, acc[2][2]);
      acc[2][3] = fmaf(xv.z, wv.w, acc[2][3]);
      acc[3][0] = fmaf(xv.w, wv.x, acc[3][0]);
      acc[3][1] = fmaf(xv.w, wv.y, acc[3][1]);
      acc[3][2] = fmaf(xv.w, wv.z, acc[3][2]);
      acc[3][3] = fmaf(xv.w, wv.w, acc[3][3]);
    }
  }

#pragma unroll
  for (int i = 0; i < 4; ++i) {
    int m = m0 + r0 + i;
    if (m >= M) continue;
    float* yr = Y + (size_t)m * 128;
    const float* rr = R ? (R + (size_t)m * 128) : (const float*)0;
#pragma unroll
    for (int j = 0; j < 4; ++j) {
      int c = c0 + j;
      float v = acc[i][j] + Bv[c];
      if (act) v = ssp_f(v);
      if (rr) v += rr[c];
      yr[c] = v;
    }
  }
}

// ---------------- conv: per-node gather over CSR edges --------------------
// one wave per node; lane holds 2 channels.
__global__ __launch_bounds__(256) void k_conv(
    const int4* __restrict__ csr, const int* __restrict__ ptr,
    const float* __restrict__ T, const float* __restrict__ hw,
    float* __restrict__ conv, int N)
{
  int wid = (blockIdx.x * 256 + threadIdx.x) >> 6;
  int lane = threadIdx.x & 63;
  if (wid >= N) return;
  int s = ptr[wid], e = ptr[wid + 1];
  float ax = 0.f, ay = 0.f;
  for (int j = s; j < e; ++j) {
    int4 pk = csr[j];
    int row = pk.x;
    int i0 = pk.y;
    float frac = __int_as_float(pk.z);
    float Cc = __int_as_float(pk.w);
    const float* t0 = T + (size_t)i0 * 128 + lane * 2;
    float2 a = *(const float2*)t0;
    float2 b = *(const float2*)(t0 + 128);
    float2 hv = *(const float2*)(hw + (size_t)row * 128 + lane * 2);
    float wx = fmaf(frac, b.x - a.x, a.x) * Cc;
    float wy = fmaf(frac, b.y - a.y, a.y) * Cc;
    ax = fmaf(wx, hv.x, ax);
    ay = fmaf(wy, hv.y, ay);
  }
  *(float2*)(conv + (size_t)wid * 128 + lane * 2) = make_float2(ax, ay);
}

// ---------------- head: y = ssp(h@w1+b1)@w2+b2, segment-sum by batch ------
__global__ __launch_bounds__(256) void k_head(
    const float* __restrict__ h, const float* __restrict__ w1,
    const float* __restrict__ b1, const float* __restrict__ w2,
    const float* __restrict__ b2, const int* __restrict__ batch,
    float* __restrict__ out, int N)
{
  int wid = (blockIdx.x * 256 + threadIdx.x) >> 6;
  int lane = threadIdx.x & 63;
  if (wid >= N) return;
  const float* hr = h + (size_t)wid * 128;
  float acc = b1[lane];
#pragma unroll 8
  for (int k = 0; k < 128; ++k)
    acc = fmaf(hr[k], w1[k * 64 + lane], acc);
  float t = ssp_f(acc) * w2[lane];
#pragma unroll
  for (int m = 32; m; m >>= 1) t += __shfl_xor(t, m);
  if (lane == 0) atomicAdd(&out[batch[wid]], t + b2[0]);
}

extern "C" void kernel_launch(void* const* d_in, const int* in_sizes, int n_in,
                              void* d_out, int out_size, void* d_ws, size_t ws_size,
                              hipStream_t stream) {
  (void)n_in; (void)ws_size;
  const float* pos     = (const float*)d_in[0];
  const int*   z       = (const int*)d_in[1];
  const int*   batch   = (const int*)d_in[2];
  const int*   ei      = (const int*)d_in[3];
  const float* emb     = (const float*)d_in[4];
  const float* mlp_w1  = (const float*)d_in[5];
  const float* mlp_b1  = (const float*)d_in[6];
  const float* mlp_w2  = (const float*)d_in[7];
  const float* mlp_b2  = (const float*)d_in[8];
  const float* aw_w    = (const float*)d_in[9];
  const float* aw_b    = (const float*)d_in[10];
  const float* out_w1  = (const float*)d_in[11];
  const float* out_b1  = (const float*)d_in[12];
  const float* out_w2  = (const float*)d_in[13];
  const float* out_b2  = (const float*)d_in[14];
  const float* head_w1 = (const float*)d_in[15];
  const float* head_b1 = (const float*)d_in[16];
  const float* head_w2 = (const float*)d_in[17];
  const float* head_b2 = (const float*)d_in[18];

  const int N  = in_sizes[0] / 3;
  const int E  = in_sizes[3] / 2;
  const int NG = out_size;
  const int L  = in_sizes[5] / (NG_GAUSS * HID);

  char* ws = (char*)d_ws;
  size_t off = 0;
  auto alloc = [&](size_t bytes) -> void* {
    off = (off + 255) & ~(size_t)255;
    void* p = ws + off;
    off += bytes;
    return p;
  };

  const size_t nh_bytes = (size_t)N * HID * 4;
  // h aliases epack (both used at disjoint times); conv aliases EA; tmp aliases T1
  float* h_buf   = (float*)alloc(nh_bytes > (size_t)E * 16 ? nh_bytes : (size_t)E * 16);
  int4*  epack   = (int4*)h_buf;
  float* hw_buf  = (float*)alloc(nh_bytes);
  float* conv_buf= (float*)alloc(nh_bytes > (size_t)TBL_P * 64 * 4 ? nh_bytes : (size_t)TBL_P * 64 * 4);
  float* EA      = conv_buf;
  float* tmp_buf = (float*)alloc(nh_bytes > (size_t)TBL_P * HID * 4 ? nh_bytes : (size_t)TBL_P * HID * 4);
  float* T1      = tmp_buf;
  int4*  csr     = (int4*)alloc((size_t)E * 16);
  float* T       = (float*)alloc((size_t)L * TBL_P * HID * 4);
  int*   deg     = (int*)alloc((size_t)N * 4);
  int*   ptr     = (int*)alloc((size_t)(N + 1) * 4);
  int*   cursor  = (int*)alloc((size_t)N * 4);

  hipMemsetAsync(deg, 0, (size_t)N * 4, stream);
  hipMemsetAsync(cursor, 0, (size_t)N * 4, stream);
  hipMemsetAsync(d_out, 0, (size_t)NG * 4, stream);

  int egrid = (E + 255) / 256;
  k_edge_pre<<<egrid, 256, 0, stream>>>(pos, ei, E, epack, deg);
  k_scan<<<1, 1024, 0, stream>>>(deg, ptr, N);
  k_csr_scatter<<<egrid, 256, 0, stream>>>(ei + E, epack, ptr, cursor, csr, E);

  // filter tables: T_l(d) = ssp(ssp(ea(d)@w1+b1)@w2+b2), cutoff C applied per edge
  k_ea_build<<<TBL_P, 64, 0, stream>>>(EA);
  for (int l = 0; l < L; ++l) {
    k_gemm<<<TBL_P / 32, 256, 0, stream>>>(
        EA, 64, mlp_w1 + (size_t)l * NG_GAUSS * HID, mlp_b1 + (size_t)l * HID,
        (const float*)0, T1, TBL_P, NG_GAUSS, 1);
    k_gemm<<<TBL_P / 32, 256, 0, stream>>>(
        T1, HID, mlp_w2 + (size_t)l * HID * HID, mlp_b2 + (size_t)l * HID,
        (const float*)0, T + (size_t)l * TBL_P * HID, TBL_P, HID, 1);
  }

  k_h_init<<<(N * 32 + 255) / 256, 256, 0, stream>>>(
      (const float4*)emb, z, (float4*)h_buf, N);

  int ngrid = (N + 31) / 32;
  int wgrid = (N * 64 + 255) / 256;
  for (int l = 0; l < L; ++l) {
    k_gemm<<<ngrid, 256, 0, stream>>>(
        h_buf, HID, aw_w + (size_t)l * HID * HID, aw_b + (size_t)l * HID,
        (const float*)0, hw_buf, N, HID, 0);
    k_conv<<<wgrid, 256, 0, stream>>>(
        csr, ptr, T + (size_t)l * TBL_P * HID, hw_buf, conv_buf, N);
    k_gemm<<<ngrid, 256, 0, stream>>>(
        conv_buf, HID, out_w1 + (size_t)l * HID * HID, out_b1 + (size_t)l * HID,
        (const float*)0, tmp_buf, N, HID, 1);
    k_gemm<<<ngrid, 256, 0, stream>>>(
        tmp_buf, HID, out_w2 + (size_t)l * HID * HID, out_b2 + (size_t)l * HID,
        h_buf, h_buf, N, HID, 0);
  }

  k_head<<<wgrid, 256, 0, stream>>>(
      h_buf, head_w1, head_b1, head_w2, head_b2, batch, (float*)d_out, N);
}

// Round 2
// 1095.249 us; speedup vs baseline: 1.5372x; 1.5372x over previous
//
#include <hip/hip_runtime.h>
#include <math.h>

#define HID 128
#define NG_GAUSS 50
#define TBL_P 4096
#define TBL_DMAX 12.8f
#define TBL_DT (TBL_DMAX / (float)TBL_P)
#define TBL_INV_DT ((float)TBL_P / TBL_DMAX)
#define PI_F 3.14159265358979323846f

typedef short bf16x8 __attribute__((ext_vector_type(8)));
typedef float f32x4 __attribute__((ext_vector_type(4)));

__device__ __forceinline__ float ssp_f(float x) {
  return fmaxf(x, 0.f) + log1pf(expf(-fabsf(x))) - 0.69314718055994530942f;
}
__device__ __forceinline__ unsigned short f2bf(float x) {
  unsigned u = __float_as_uint(x);
  unsigned r = (u + 0x7FFFu + ((u >> 16) & 1u)) >> 16;
  return (unsigned short)r;
}
__device__ __forceinline__ float bf2f(unsigned h) {
  return __uint_as_float(h << 16);
}

// ---------------- edge precompute: d, C, table coords, degree histogram ----
__global__ __launch_bounds__(256) void k_edge_pre(
    const float* __restrict__ pos, const int* __restrict__ ei,
    int E, int4* __restrict__ epack, int* __restrict__ deg)
{
  int e = blockIdx.x * 256 + threadIdx.x;
  if (e >= E) return;
  int r = ei[e];
  int c = ei[E + e];
  float dx = pos[3*r+0] - pos[3*c+0];
  float dy = pos[3*r+1] - pos[3*c+1];
  float dz = pos[3*r+2] - pos[3*c+2];
  float d = sqrtf(dx*dx + dy*dy + dz*dz);
  float Cc = 0.5f * (cosf(d * (PI_F / 10.0f)) + 1.0f);
  float u = d * TBL_INV_DT;
  int i0 = (int)u;
  if (i0 > TBL_P - 2) i0 = TBL_P - 2;
  float frac = fminf(u - (float)i0, 1.0f);
  epack[e] = make_int4(r, i0, __float_as_int(frac), __float_as_int(Cc));
  atomicAdd(&deg[c], 1);
}

// ---------------- exclusive scan over degrees (single block) --------------
__global__ __launch_bounds__(1024) void k_scan(
    const int* __restrict__ deg, int* __restrict__ ptr, int N)
{
  __shared__ int s[1024];
  __shared__ int carry;
  int t = threadIdx.x;
  if (t == 0) carry = 0;
  __syncthreads();
  for (int base = 0; base < N; base += 1024) {
    int v = (base + t < N) ? deg[base + t] : 0;
    s[t] = v;
    __syncthreads();
    for (int off = 1; off < 1024; off <<= 1) {
      int x = (t >= off) ? s[t - off] : 0;
      __syncthreads();
      s[t] += x;
      __syncthreads();
    }
    int my = carry + s[t] - v;
    if (base + t < N) ptr[base + t] = my;
    __syncthreads();
    if (t == 1023) carry += s[1023];
    __syncthreads();
  }
  if (t == 0) ptr[N] = carry;
}

// ---------------- scatter edges into CSR order ----------------------------
__global__ __launch_bounds__(256) void k_csr_scatter(
    const int* __restrict__ col, const int4* __restrict__ epack,
    const int* __restrict__ ptr, int* __restrict__ cursor,
    int4* __restrict__ csr, int E)
{
  int e = blockIdx.x * 256 + threadIdx.x;
  if (e >= E) return;
  int c = col[e];
  int slot = ptr[c] + atomicAdd(&cursor[c], 1);
  csr[slot] = epack[e];
}

// ---------------- gaussian feature table [TBL_P][64] (zero-padded) --------
__global__ void k_ea_build(float* __restrict__ EA)
{
  int p = blockIdx.x;
  int g = threadIdx.x; // 64 threads
  float dp = p * TBL_DT;
  float v = 0.f;
  if (g < NG_GAUSS) {
    float step = 10.0f / 49.0f;
    float off = g * step;
    float coeff = -0.5f / (step * step);
    float t = dp - off;
    v = expf(coeff * t * t);
  }
  EA[p * 64 + g] = v;
}

// ---------------- h init: h = emb[z] --------------------------------------
__global__ __launch_bounds__(256) void k_h_init(
    const float4* __restrict__ emb4, const int* __restrict__ z,
    float4* __restrict__ h4, int N)
{
  int idx = blockIdx.x * 256 + threadIdx.x;
  if (idx >= N * 32) return;
  int n = idx >> 5, c = idx & 31;
  h4[idx] = emb4[z[n] * 32 + c];
}

// ---------------- MFMA GEMM: Y = act(X@W + b) [+ R], bf16 inputs ----------
// X fp32 [M,ldx] (ldx<=128, zero-padded logically to K=128), W fp32 [Kw,128]
// (zero-padded to 128 rows). Batched over blockIdx.y via strides (elements).
// Block: 256 threads (4 waves), tile 64 rows x 128 cols.
__global__ __launch_bounds__(256) void k_mgemm(
    const float* __restrict__ X, int ldx, long xstride,
    const float* __restrict__ W, int Kw, long wstride,
    const float* __restrict__ Bv, long bstride,
    const float* __restrict__ R,
    void* __restrict__ Y, long ystride,
    int M, int act, int out_bf16)
{
  __shared__ unsigned short Xs[64][128];   // bf16, 16B-chunk XOR swizzled
  __shared__ unsigned short Wt[128][128];  // bf16, Wt[n][k], swizzled

  const int l = blockIdx.y;
  const float* Xb = X + (long)l * xstride;
  const float* Wb = W + (long)l * wstride;
  const float* Bb = Bv + (long)l * bstride;
  const int m0 = blockIdx.x * 64;
  const int tid = threadIdx.x;

  // stage X tile (fp32 -> bf16), swizzle: 16B chunk c -> c ^ (row&7)
  for (int idx = tid; idx < 64 * 32; idx += 256) {
    int r = idx >> 5;
    int c4 = (idx & 31) << 2;          // first fp32 col of this float4
    int m = m0 + r;
    float4 v = make_float4(0.f, 0.f, 0.f, 0.f);
    if (m < M && c4 < ldx) v = *(const float4*)&Xb[(long)m * ldx + c4];
    int chunk = c4 >> 3;
    int sw = chunk ^ (r & 7);
    *(ushort4*)&Xs[r][(sw << 3) | (c4 & 7)] =
        make_ushort4(f2bf(v.x), f2bf(v.y), f2bf(v.z), f2bf(v.w));
  }
  // stage W transposed (Wt[n][k] bf16), coalesced reads of W rows
  for (int idx = tid; idx < 32 * 128; idx += 256) {
    int k0 = (idx >> 7) << 2;          // 0,4,...,124
    int n = idx & 127;
    float4 v;
    v.x = (k0 + 0 < Kw) ? Wb[(long)(k0 + 0) * 128 + n] : 0.f;
    v.y = (k0 + 1 < Kw) ? Wb[(long)(k0 + 1) * 128 + n] : 0.f;
    v.z = (k0 + 2 < Kw) ? Wb[(long)(k0 + 2) * 128 + n] : 0.f;
    v.w = (k0 + 3 < Kw) ? Wb[(long)(k0 + 3) * 128 + n] : 0.f;
    int chunk = k0 >> 3;
    int sw = chunk ^ (n & 7);
    *(ushort4*)&Wt[n][(sw << 3) | (k0 & 7)] =
        make_ushort4(f2bf(v.x), f2bf(v.y), f2bf(v.z), f2bf(v.w));
  }
  __syncthreads();

  const int wv = tid >> 6;
  const int lane = tid & 63;
  const int lr = lane & 15;
  const int lk = lane >> 4;

  f32x4 acc[8];
#pragma unroll
  for (int i = 0; i < 8; ++i)
#pragma unroll
    for (int j = 0; j < 4; ++j) acc[i][j] = 0.f;

  const int arow = (wv << 4) | lr;
  const int axor = arow & 7;
#pragma unroll
  for (int kc = 0; kc < 4; ++kc) {
    int chunk = (kc << 2) | lk;
    bf16x8 a = *(bf16x8*)&Xs[arow][((chunk ^ axor) << 3)];
#pragma unroll
    for (int nt = 0; nt < 8; ++nt) {
      int n = (nt << 4) | lr;
      bf16x8 b = *(bf16x8*)&Wt[n][((chunk ^ (n & 7)) << 3)];
      acc[nt] = __builtin_amdgcn_mfma_f32_16x16x32_bf16(a, b, acc[nt], 0, 0, 0);
    }
  }

  // epilogue: D row=(lane>>4)*4+reg, col=lane&15 (per m89-verified mapping)
#pragma unroll
  for (int nt = 0; nt < 8; ++nt) {
    int col = (nt << 4) | lr;
    float bv = Bb[col];
#pragma unroll
    for (int r2 = 0; r2 < 4; ++r2) {
      int m = m0 + (wv << 4) + (lk << 2) + r2;
      if (m >= M) continue;
      float v = acc[nt][r2] + bv;
      if (act) v = ssp_f(v);
      if (R) v += R[(long)m * 128 + col];
      if (out_bf16)
        ((unsigned short*)Y)[(long)l * ystride + (long)m * 128 + col] = f2bf(v);
      else
        ((float*)Y)[(long)l * ystride + (long)m * 128 + col] = v;
    }
  }
}

// ---------------- conv: per-node gather over CSR edges (bf16 T, hw) -------
__global__ __launch_bounds__(256) void k_conv(
    const int4* __restrict__ csr, const int* __restrict__ ptr,
    const unsigned short* __restrict__ T, const unsigned short* __restrict__ hw,
    float* __restrict__ conv, int N)
{
  int wid = (blockIdx.x * 256 + threadIdx.x) >> 6;
  int lane = threadIdx.x & 63;
  if (wid >= N) return;
  int s = ptr[wid], e = ptr[wid + 1];
  float ax = 0.f, ay = 0.f;
  for (int j = s; j < e; ++j) {
    int4 pk = csr[j];
    float frac = __int_as_float(pk.z);
    float Cc = __int_as_float(pk.w);
    const unsigned short* t0 = T + (size_t)pk.y * 128 + lane * 2;
    unsigned a = *(const unsigned*)t0;
    unsigned b = *(const unsigned*)(t0 + 128);
    unsigned hv = *(const unsigned*)(hw + (size_t)pk.x * 128 + lane * 2);
    float a0 = bf2f(a & 0xffffu), a1 = bf2f(a >> 16);
    float b0 = bf2f(b & 0xffffu), b1 = bf2f(b >> 16);
    float h0 = bf2f(hv & 0xffffu), h1 = bf2f(hv >> 16);
    float wx = fmaf(frac, b0 - a0, a0) * Cc;
    float wy = fmaf(frac, b1 - a1, a1) * Cc;
    ax = fmaf(wx, h0, ax);
    ay = fmaf(wy, h1, ay);
  }
  *(float2*)(conv + (size_t)wid * 128 + lane * 2) = make_float2(ax, ay);
}

// ---------------- head: y = ssp(h@w1+b1)@w2+b2, segment-sum by batch ------
__global__ __launch_bounds__(256) void k_head(
    const float* __restrict__ h, const float* __restrict__ w1,
    const float* __restrict__ b1, const float* __restrict__ w2,
    const float* __restrict__ b2, const int* __restrict__ batch,
    float* __restrict__ out, int N)
{
  int wid = (blockIdx.x * 256 + threadIdx.x) >> 6;
  int lane = threadIdx.x & 63;
  if (wid >= N) return;
  const float* hr = h + (size_t)wid * 128;
  float acc = b1[lane];
#pragma unroll 8
  for (int k = 0; k < 128; ++k)
    acc = fmaf(hr[k], w1[k * 64 + lane], acc);
  float t = ssp_f(acc) * w2[lane];
#pragma unroll
  for (int m = 32; m; m >>= 1) t += __shfl_xor(t, m);
  if (lane == 0) atomicAdd(&out[batch[wid]], t + b2[0]);
}

extern "C" void kernel_launch(void* const* d_in, const int* in_sizes, int n_in,
                              void* d_out, int out_size, void* d_ws, size_t ws_size,
                              hipStream_t stream) {
  (void)n_in; (void)ws_size;
  const float* pos     = (const float*)d_in[0];
  const int*   z       = (const int*)d_in[1];
  const int*   batch   = (const int*)d_in[2];
  const int*   ei      = (const int*)d_in[3];
  const float* emb     = (const float*)d_in[4];
  const float* mlp_w1  = (const float*)d_in[5];
  const float* mlp_b1  = (const float*)d_in[6];
  const float* mlp_w2  = (const float*)d_in[7];
  const float* mlp_b2  = (const float*)d_in[8];
  const float* aw_w    = (const float*)d_in[9];
  const float* aw_b    = (const float*)d_in[10];
  const float* out_w1  = (const float*)d_in[11];
  const float* out_b1  = (const float*)d_in[12];
  const float* out_w2  = (const float*)d_in[13];
  const float* out_b2  = (const float*)d_in[14];
  const float* head_w1 = (const float*)d_in[15];
  const float* head_b1 = (const float*)d_in[16];
  const float* head_w2 = (const float*)d_in[17];
  const float* head_b2 = (const float*)d_in[18];

  const int N  = in_sizes[0] / 3;
  const int E  = in_sizes[3] / 2;
  const int NG = out_size;
  const int L  = in_sizes[5] / (NG_GAUSS * HID);

  char* ws = (char*)d_ws;
  size_t off = 0;
  auto alloc = [&](size_t bytes) -> void* {
    off = (off + 255) & ~(size_t)255;
    void* p = ws + off;
    off += bytes;
    return p;
  };

  const size_t nh_bytes = (size_t)N * HID * 4;
  const size_t t1_bytes = (size_t)L * TBL_P * HID * 4;
  // h aliases epack; conv aliases EA; tmp aliases T1 (disjoint lifetimes)
  float* h_buf   = (float*)alloc(nh_bytes > (size_t)E * 16 ? nh_bytes : (size_t)E * 16);
  int4*  epack   = (int4*)h_buf;
  unsigned short* hw_buf = (unsigned short*)alloc((size_t)N * HID * 2);
  float* conv_buf= (float*)alloc(nh_bytes > (size_t)TBL_P * 64 * 4 ? nh_bytes : (size_t)TBL_P * 64 * 4);
  float* EA      = conv_buf;
  float* tmp_buf = (float*)alloc(nh_bytes > t1_bytes ? nh_bytes : t1_bytes);
  float* T1      = tmp_buf;
  int4*  csr     = (int4*)alloc((size_t)E * 16);
  unsigned short* T = (unsigned short*)alloc((size_t)L * TBL_P * HID * 2);
  int*   deg     = (int*)alloc((size_t)N * 4);
  int*   ptr     = (int*)alloc((size_t)(N + 1) * 4);
  int*   cursor  = (int*)alloc((size_t)N * 4);

  hipMemsetAsync(deg, 0, (size_t)N * 4, stream);
  hipMemsetAsync(cursor, 0, (size_t)N * 4, stream);
  hipMemsetAsync(d_out, 0, (size_t)NG * 4, stream);

  int egrid = (E + 255) / 256;
  k_edge_pre<<<egrid, 256, 0, stream>>>(pos, ei, E, epack, deg);
  k_scan<<<1, 1024, 0, stream>>>(deg, ptr, N);
  k_csr_scatter<<<egrid, 256, 0, stream>>>(ei + E, epack, ptr, cursor, csr, E);

  // filter tables: T_l(d) = ssp(ssp(ea(d)@w1+b1)@w2+b2), batched over l
  k_ea_build<<<TBL_P, 64, 0, stream>>>(EA);
  k_mgemm<<<dim3(TBL_P / 64, L), 256, 0, stream>>>(
      EA, 64, 0L,
      mlp_w1, NG_GAUSS, (long)NG_GAUSS * HID,
      mlp_b1, HID, (const float*)0,
      T1, (long)TBL_P * HID, TBL_P, 1, 0);
  k_mgemm<<<dim3(TBL_P / 64, L), 256, 0, stream>>>(
      T1, HID, (long)TBL_P * HID,
      mlp_w2, HID, (long)HID * HID,
      mlp_b2, HID, (const float*)0,
      T, (long)TBL_P * HID, TBL_P, 1, 1);

  k_h_init<<<(N * 32 + 255) / 256, 256, 0, stream>>>(
      (const float4*)emb, z, (float4*)h_buf, N);

  int ngrid = (N + 63) / 64;
  int wgrid = (N * 64 + 255) / 256;
  for (int l = 0; l < L; ++l) {
    k_mgemm<<<dim3(ngrid, 1), 256, 0, stream>>>(
        h_buf, HID, 0L,
        aw_w + (size_t)l * HID * HID, HID, 0L,
        aw_b + (size_t)l * HID, 0L, (const float*)0,
        hw_buf, 0L, N, 0, 1);
    k_conv<<<wgrid, 256, 0, stream>>>(
        csr, ptr, T + (size_t)l * TBL_P * HID, hw_buf, conv_buf, N);
    k_mgemm<<<dim3(ngrid, 1), 256, 0, stream>>>(
        conv_buf, HID, 0L,
        out_w1 + (size_t)l * HID * HID, HID, 0L,
        out_b1 + (size_t)l * HID, 0L, (const float*)0,
        tmp_buf, 0L, N, 1, 0);
    k_mgemm<<<dim3(ngrid, 1), 256, 0, stream>>>(
        tmp_buf, HID, 0L,
        out_w2 + (size_t)l * HID * HID, HID, 0L,
        out_b2 + (size_t)l * HID, 0L, h_buf,
        h_buf, 0L, N, 0, 0);
  }

  k_head<<<wgrid, 256, 0, stream>>>(
      h_buf, head_w1, head_b1, head_w2, head_b2, batch, (float*)d_out, N);
}

// Round 3
// 658.174 us; speedup vs baseline: 2.5581x; 1.6641x over previous
//
#include <hip/hip_runtime.h>
#include <math.h>

#define HID 128
#define NG_GAUSS 50
#define TBL_P 4096
#define TBL_DMAX 12.8f
#define TBL_DT (TBL_DMAX / (float)TBL_P)
#define TBL_INV_DT ((float)TBL_P / TBL_DMAX)
#define PI_F 3.14159265358979323846f

typedef short bf16x8 __attribute__((ext_vector_type(8)));
typedef float f32x4 __attribute__((ext_vector_type(4)));

__device__ __forceinline__ float ssp_f(float x) {
  return fmaxf(x, 0.f) + log1pf(expf(-fabsf(x))) - 0.69314718055994530942f;
}
__device__ __forceinline__ unsigned short f2bf(float x) {
  unsigned u = __float_as_uint(x);
  unsigned r = (u + 0x7FFFu + ((u >> 16) & 1u)) >> 16;
  return (unsigned short)r;
}

// ---------------- edge precompute: pack (row, i0, frac), degree histogram --
__global__ __launch_bounds__(256) void k_edge_pre(
    const float* __restrict__ pos, const int* __restrict__ ei,
    int E, int2* __restrict__ epack, int* __restrict__ deg)
{
  int e = blockIdx.x * 256 + threadIdx.x;
  if (e >= E) return;
  int r = ei[e];
  int c = ei[E + e];
  float dx = pos[3*r+0] - pos[3*c+0];
  float dy = pos[3*r+1] - pos[3*c+1];
  float dz = pos[3*r+2] - pos[3*c+2];
  float d = sqrtf(dx*dx + dy*dy + dz*dz);
  float u = d * TBL_INV_DT;
  int i0 = (int)u;
  if (i0 > TBL_P - 2) i0 = TBL_P - 2;
  float frac = fminf(u - (float)i0, 1.0f);
  unsigned frac20 = (unsigned)(frac * 1048576.f);
  if (frac20 > 1048575u) frac20 = 1048575u;
  epack[e] = make_int2(r, (int)(((unsigned)i0 << 20) | frac20));
  atomicAdd(&deg[c], 1);
}

// ---------------- exclusive scan over degrees (single block, 2-level) -----
__global__ __launch_bounds__(1024) void k_scan(
    const int* __restrict__ deg, int* __restrict__ ptr, int N)
{
  __shared__ int wsum[16];
  int t = threadIdx.x;
  int chunk = (N + 1023) / 1024;
  int b = t * chunk;
  int e2 = min(b + chunk, N);
  int s = 0;
  for (int i = b; i < e2; ++i) s += deg[i];
  int lane = t & 63, w = t >> 6;
  int ps = s;
  for (int o = 1; o < 64; o <<= 1) { int x = __shfl_up(ps, o); if (lane >= o) ps += x; }
  if (lane == 63) wsum[w] = ps;
  __syncthreads();
  if (w == 0 && lane < 16) {
    int v = wsum[lane];
    int pv = v;
    for (int o = 1; o < 16; o <<= 1) { int x = __shfl_up(pv, o); if (lane >= o) pv += x; }
    wsum[lane] = pv - v;  // exclusive
  }
  __syncthreads();
  int base = wsum[w] + ps - s;
  for (int i = b; i < e2; ++i) { ptr[i] = base; base += deg[i]; }
  if (t == 1023) ptr[N] = base;
}

// ---------------- scatter edges into CSR order ----------------------------
__global__ __launch_bounds__(256) void k_csr_scatter(
    const int* __restrict__ col, const int2* __restrict__ epack,
    const int* __restrict__ ptr, int* __restrict__ cursor,
    int2* __restrict__ csr, int E)
{
  int e = blockIdx.x * 256 + threadIdx.x;
  if (e >= E) return;
  int c = col[e];
  int slot = ptr[c] + atomicAdd(&cursor[c], 1);
  csr[slot] = epack[e];
}

// ---------------- weight prep: bf16, transposed [n][k], chunk-XOR swizzle -
__global__ __launch_bounds__(256) void k_wprep(
    const float* __restrict__ aw_w, const float* __restrict__ out_w1,
    const float* __restrict__ out_w2, const float* __restrict__ mlp_w2,
    const float* __restrict__ mlp_w1,
    unsigned short* __restrict__ awt, unsigned short* __restrict__ o1t,
    unsigned short* __restrict__ o2t, unsigned short* __restrict__ m2t,
    unsigned short* __restrict__ m1t)
{
  __shared__ float Wl[64][132];
  int l = blockIdx.x, t = blockIdx.y;
  const float* src; unsigned short* dst; int K;
  switch (t) {
    case 0:  src = aw_w;   dst = awt; K = 128; break;
    case 1:  src = out_w1; dst = o1t; K = 128; break;
    case 2:  src = out_w2; dst = o2t; K = 128; break;
    case 3:  src = mlp_w2; dst = m2t; K = 128; break;
    default: src = mlp_w1; dst = m1t; K = NG_GAUSS; break;
  }
  src += (long)l * K * 128;
  dst += (long)l * 128 * 128;
  const int tid = threadIdx.x;
  for (int k0 = 0; k0 < 128; k0 += 64) {
    __syncthreads();
    for (int idx = tid; idx < 64 * 128; idx += 256) {
      int kk = idx >> 7, n = idx & 127;
      int k = k0 + kk;
      Wl[kk][n] = (k < K) ? src[(long)k * 128 + n] : 0.f;
    }
    __syncthreads();
    for (int idx = tid; idx < 128 * 8; idx += 256) {
      int n = idx >> 3, pl = idx & 7;
      int p = (k0 >> 3) + pl;          // stored chunk position
      int q = p ^ (n & 7);             // logical chunk (same 8-chunk half)
      int kk = (q << 3) - k0;
      ushort4 lo = make_ushort4(f2bf(Wl[kk+0][n]), f2bf(Wl[kk+1][n]),
                                f2bf(Wl[kk+2][n]), f2bf(Wl[kk+3][n]));
      ushort4 hi = make_ushort4(f2bf(Wl[kk+4][n]), f2bf(Wl[kk+5][n]),
                                f2bf(Wl[kk+6][n]), f2bf(Wl[kk+7][n]));
      *(ushort4*)(dst + ((long)n << 7) + (p << 3)) = lo;
      *(ushort4*)(dst + ((long)n << 7) + (p << 3) + 4) = hi;
    }
  }
}

// ---------------- gaussian feature table bf16 [TBL_P][128] zero-padded ----
__global__ void k_ea_build(unsigned short* __restrict__ EA)
{
  int p = blockIdx.x;
  int g = threadIdx.x; // 128 threads
  float v = 0.f;
  if (g < NG_GAUSS) {
    float step = 10.0f / 49.0f;
    float off = g * step;
    float coeff = -0.5f / (step * step);
    float t = p * TBL_DT - off;
    v = expf(coeff * t * t);
  }
  EA[p * 128 + g] = f2bf(v);
}

// ---------------- h init: h = emb[z] (fp32 + bf16 copy) -------------------
__global__ __launch_bounds__(256) void k_h_init(
    const float4* __restrict__ emb4, const int* __restrict__ z,
    float4* __restrict__ h4, ushort4* __restrict__ hb4, int N)
{
  int idx = blockIdx.x * 256 + threadIdx.x;
  if (idx >= N * 32) return;
  int n = idx >> 5, c = idx & 31;
  float4 v = emb4[z[n] * 32 + c];
  h4[idx] = v;
  hb4[idx] = make_ushort4(f2bf(v.x), f2bf(v.y), f2bf(v.z), f2bf(v.w));
}

// ---------------- fused GEMM chain ----------------------------------------
// Stage A (if Wa): tmp = ssp(X@Wa + ba)            (X bf16 [M][128])
// Stage B:         v = tmp@Wb + bb; [ssp]; [+R]; [*C(row)]; -> out1 (f32|bf16)
// Stage C (if Wc): out2 = v_bf16@Wc + bc  (bf16)
// Weights pre-transposed/swizzled bf16 [128][128]. Batched over blockIdx.y.
__global__ __launch_bounds__(256) void k_fused(
    const unsigned short* __restrict__ X, long xstr,
    const unsigned short* __restrict__ Wa, long wastr,
    const float* __restrict__ ba, long bastr,
    const unsigned short* __restrict__ Wb, long wbstr,
    const float* __restrict__ bb, long bbstr,
    const float* __restrict__ R,
    void* __restrict__ out1, long o1str, int o1_bf16, int actB, int mulC,
    const unsigned short* __restrict__ Wc, const float* __restrict__ bc,
    unsigned short* __restrict__ out2,
    int M)
{
  __shared__ unsigned short Xs[64][128];
  __shared__ unsigned short U[128][128];
  __shared__ unsigned short V[128][128];

  const int l = blockIdx.y;
  const int m0 = blockIdx.x * 64;
  const int tid = threadIdx.x;
  const unsigned short* Xb = X + (long)l * xstr;

  // stage X tile (bf16 16B chunks, XOR swizzle on chunk index)
  for (int idx = tid; idx < 1024; idx += 256) {
    int r = idx >> 4, c = idx & 15;
    int m = m0 + r;
    int4 v = make_int4(0, 0, 0, 0);
    if (m < M) v = *(const int4*)(Xb + (long)m * 128 + c * 8);
    *(int4*)&Xs[r][(c ^ (r & 7)) << 3] = v;
  }
  if (Wa) {
    const int4* s = (const int4*)(Wa + (long)l * wastr);
    int4* d = (int4*)U;
    for (int i = tid; i < 2048; i += 256) d[i] = s[i];
  }
  {
    const int4* s = (const int4*)(Wb + (long)l * wbstr);
    int4* d = (int4*)V;
    for (int i = tid; i < 2048; i += 256) d[i] = s[i];
  }
  __syncthreads();

  const int wv = tid >> 6, lane = tid & 63;
  const int lr = lane & 15, lk = lane >> 4;
  const int arow = (wv << 4) | lr;

  f32x4 acc[8];
  auto zacc = [&]() {
#pragma unroll
    for (int i = 0; i < 8; ++i)
#pragma unroll
      for (int j = 0; j < 4; ++j) acc[i][j] = 0.f;
  };
  auto gemm = [&](const unsigned short* Wl) {
#pragma unroll
    for (int kc = 0; kc < 4; ++kc) {
      int q = (kc << 2) | lk;
      bf16x8 a = *(const bf16x8*)&Xs[arow][(q ^ (arow & 7)) << 3];
#pragma unroll
      for (int nt = 0; nt < 8; ++nt) {
        int n = (nt << 4) | lr;
        bf16x8 b = *(const bf16x8*)(Wl + n * 128 + ((q ^ (n & 7)) << 3));
        acc[nt] = __builtin_amdgcn_mfma_f32_16x16x32_bf16(a, b, acc[nt], 0, 0, 0);
      }
    }
  };

  if (Wa) {
    const float* bab = ba + (long)l * bastr;
    zacc();
    gemm(&U[0][0]);
    __syncthreads();                   // all stage-A LDS reads done
#pragma unroll
    for (int nt = 0; nt < 8; ++nt) {
      int col = (nt << 4) | lr;
      float bv = bab[col];
#pragma unroll
      for (int r2 = 0; r2 < 4; ++r2) {
        int row = (wv << 4) | (lk << 2) | r2;
        float v2 = ssp_f(acc[nt][r2] + bv);
        int cch = col >> 3;
        Xs[row][((cch ^ (row & 7)) << 3) | (col & 7)] = f2bf(v2);
      }
    }
    if (Wc) {                          // refill U with Wc (read at stage C)
      const int4* s = (const int4*)Wc;
      int4* d = (int4*)U;
      for (int i = tid; i < 2048; i += 256) d[i] = s[i];
    }
    __syncthreads();
  }

  const float* bbb = bb + (long)l * bbstr;
  zacc();
  gemm(&V[0][0]);
  __syncthreads();                     // stage-B Xs reads done before overwrite

#pragma unroll
  for (int nt = 0; nt < 8; ++nt) {
    int col = (nt << 4) | lr;
    float bv = bbb[col];
#pragma unroll
    for (int r2 = 0; r2 < 4; ++r2) {
      int row = (wv << 4) | (lk << 2) | r2;
      int m = m0 + row;
      float v2 = acc[nt][r2] + bv;
      if (actB) v2 = ssp_f(v2);
      if (R && m < M) v2 += R[(long)m * 128 + col];
      if (mulC) {
        float d = (float)m * TBL_DT;
        v2 *= 0.5f * (cosf(d * (PI_F / 10.0f)) + 1.0f);
      }
      if (m < M) {
        if (o1_bf16)
          ((unsigned short*)out1)[(long)l * o1str + (long)m * 128 + col] = f2bf(v2);
        else
          ((float*)out1)[(long)l * o1str + (long)m * 128 + col] = v2;
      }
      if (Wc) {
        int cch = col >> 3;
        Xs[row][((cch ^ (row & 7)) << 3) | (col & 7)] = f2bf(v2);
      }
    }
  }

  if (Wc) {
    __syncthreads();
    zacc();
    gemm(&U[0][0]);
#pragma unroll
    for (int nt = 0; nt < 8; ++nt) {
      int col = (nt << 4) | lr;
      float bv = bc[col];
#pragma unroll
      for (int r2 = 0; r2 < 4; ++r2) {
        int row = (wv << 4) | (lk << 2) | r2;
        int m = m0 + row;
        if (m < M)
          out2[(long)m * 128 + col] = f2bf(acc[nt][r2] + bv);
      }
    }
  }
}

// ---------------- conv: per-node gather, 4-way unrolled chains ------------
#define CONV_EDGE(PK, AX, AY) {                                              \
    unsigned pr = (unsigned)(PK).y;                                          \
    int i0 = (int)(pr >> 20);                                                \
    float frac = (float)(pr & 0xFFFFFu) * (1.f / 1048576.f);                 \
    const unsigned short* t0 = T + ((size_t)i0 << 7) + (lane << 1);          \
    unsigned a = *(const unsigned*)t0;                                       \
    unsigned b = *(const unsigned*)(t0 + 128);                               \
    unsigned hv = *(const unsigned*)(hw + ((size_t)(PK).x << 7) + (lane << 1)); \
    float a0 = __uint_as_float(a << 16), a1 = __uint_as_float(a & 0xffff0000u); \
    float b0 = __uint_as_float(b << 16), b1 = __uint_as_float(b & 0xffff0000u); \
    float h0 = __uint_as_float(hv << 16), h1 = __uint_as_float(hv & 0xffff0000u); \
    float wx = fmaf(frac, b0 - a0, a0);                                      \
    float wy = fmaf(frac, b1 - a1, a1);                                      \
    AX = fmaf(wx, h0, AX); AY = fmaf(wy, h1, AY); }

__global__ __launch_bounds__(256) void k_conv(
    const int2* __restrict__ csr, const int* __restrict__ ptr,
    const unsigned short* __restrict__ T, const unsigned short* __restrict__ hw,
    unsigned short* __restrict__ convb, int N)
{
  int wid = (blockIdx.x * 256 + threadIdx.x) >> 6;
  int lane = threadIdx.x & 63;
  if (wid >= N) return;
  int s = ptr[wid], e = ptr[wid + 1];
  float ax0 = 0.f, ay0 = 0.f, ax1 = 0.f, ay1 = 0.f;
  float ax2 = 0.f, ay2 = 0.f, ax3 = 0.f, ay3 = 0.f;
  int j = s;
  for (; j + 4 <= e; j += 4) {
    int2 p0 = csr[j], p1 = csr[j + 1], p2 = csr[j + 2], p3 = csr[j + 3];
    CONV_EDGE(p0, ax0, ay0);
    CONV_EDGE(p1, ax1, ay1);
    CONV_EDGE(p2, ax2, ay2);
    CONV_EDGE(p3, ax3, ay3);
  }
  for (; j < e; ++j) {
    int2 p = csr[j];
    CONV_EDGE(p, ax0, ay0);
  }
  float ax = (ax0 + ax1) + (ax2 + ax3);
  float ay = (ay0 + ay1) + (ay2 + ay3);
  unsigned outw = (unsigned)f2bf(ax) | ((unsigned)f2bf(ay) << 16);
  *(unsigned*)(convb + ((size_t)wid << 7) + (lane << 1)) = outw;
}

// ---------------- head: y = ssp(h@w1+b1)@w2+b2, segment-sum by batch ------
__global__ __launch_bounds__(256) void k_head(
    const float* __restrict__ h, const float* __restrict__ w1,
    const float* __restrict__ b1, const float* __restrict__ w2,
    const float* __restrict__ b2, const int* __restrict__ batch,
    float* __restrict__ out, int N)
{
  int wid = (blockIdx.x * 256 + threadIdx.x) >> 6;
  int lane = threadIdx.x & 63;
  if (wid >= N) return;
  const float* hr = h + (size_t)wid * 128;
  float acc = b1[lane];
#pragma unroll 8
  for (int k = 0; k < 128; ++k)
    acc = fmaf(hr[k], w1[k * 64 + lane], acc);
  float t = ssp_f(acc) * w2[lane];
#pragma unroll
  for (int m = 32; m; m >>= 1) t += __shfl_xor(t, m);
  if (lane == 0) atomicAdd(&out[batch[wid]], t + b2[0]);
}

extern "C" void kernel_launch(void* const* d_in, const int* in_sizes, int n_in,
                              void* d_out, int out_size, void* d_ws, size_t ws_size,
                              hipStream_t stream) {
  (void)n_in; (void)ws_size;
  const float* pos     = (const float*)d_in[0];
  const int*   z       = (const int*)d_in[1];
  const int*   batch   = (const int*)d_in[2];
  const int*   ei      = (const int*)d_in[3];
  const float* emb     = (const float*)d_in[4];
  const float* mlp_w1  = (const float*)d_in[5];
  const float* mlp_b1  = (const float*)d_in[6];
  const float* mlp_w2  = (const float*)d_in[7];
  const float* mlp_b2  = (const float*)d_in[8];
  const float* aw_w    = (const float*)d_in[9];
  const float* aw_b    = (const float*)d_in[10];
  const float* out_w1  = (const float*)d_in[11];
  const float* out_b1  = (const float*)d_in[12];
  const float* out_w2  = (const float*)d_in[13];
  const float* out_b2  = (const float*)d_in[14];
  const float* head_w1 = (const float*)d_in[15];
  const float* head_b1 = (const float*)d_in[16];
  const float* head_w2 = (const float*)d_in[17];
  const float* head_b2 = (const float*)d_in[18];

  const int N  = in_sizes[0] / 3;
  const int E  = in_sizes[3] / 2;
  const int NG = out_size;
  const int L  = in_sizes[5] / (NG_GAUSS * HID);

  char* ws = (char*)d_ws;
  size_t off = 0;
  auto alloc = [&](size_t bytes) -> void* {
    off = (off + 255) & ~(size_t)255;
    void* p = ws + off;
    off += bytes;
    return p;
  };

  const size_t nh = (size_t)N * HID;
  const size_t ep_bytes = (size_t)E * 8;
  float* h_buf = (float*)alloc(nh * 4 > ep_bytes ? nh * 4 : ep_bytes);
  int2*  epack = (int2*)h_buf;                  // alias (disjoint lifetime)
  unsigned short* hb    = (unsigned short*)alloc(nh * 2);
  unsigned short* hw    = (unsigned short*)alloc(nh * 2);
  unsigned short* convb = (unsigned short*)alloc(
      nh * 2 > (size_t)TBL_P * 128 * 2 ? nh * 2 : (size_t)TBL_P * 128 * 2);
  unsigned short* EA    = convb;                // alias (EA used pre-conv)
  int2*  csr = (int2*)alloc((size_t)E * 8);
  unsigned short* T   = (unsigned short*)alloc((size_t)L * TBL_P * 128 * 2);
  unsigned short* awt = (unsigned short*)alloc((size_t)L * 16384 * 2);
  unsigned short* o1t = (unsigned short*)alloc((size_t)L * 16384 * 2);
  unsigned short* o2t = (unsigned short*)alloc((size_t)L * 16384 * 2);
  unsigned short* m2t = (unsigned short*)alloc((size_t)L * 16384 * 2);
  unsigned short* m1t = (unsigned short*)alloc((size_t)L * 16384 * 2);
  int* deg    = (int*)alloc((size_t)N * 4);
  int* ptr    = (int*)alloc((size_t)(N + 1) * 4);
  int* cursor = (int*)alloc((size_t)N * 4);

  hipMemsetAsync(deg, 0, (size_t)N * 4, stream);
  hipMemsetAsync(cursor, 0, (size_t)N * 4, stream);
  hipMemsetAsync(d_out, 0, (size_t)NG * 4, stream);

  int egrid = (E + 255) / 256;
  k_edge_pre<<<egrid, 256, 0, stream>>>(pos, ei, E, epack, deg);
  k_scan<<<1, 1024, 0, stream>>>(deg, ptr, N);
  k_csr_scatter<<<egrid, 256, 0, stream>>>(ei + E, epack, ptr, cursor, csr, E);

  k_wprep<<<dim3(L, 5), 256, 0, stream>>>(aw_w, out_w1, out_w2, mlp_w2, mlp_w1,
                                          awt, o1t, o2t, m2t, m1t);
  k_ea_build<<<TBL_P, 128, 0, stream>>>(EA);

  // filter tables: T_l = ssp(ssp(EA@w1+b1)@w2+b2) * C(d), bf16, batched
  k_fused<<<dim3(TBL_P / 64, L), 256, 0, stream>>>(
      EA, 0L,
      m1t, 16384L, mlp_b1, 128L,
      m2t, 16384L, mlp_b2, 128L,
      (const float*)0,
      T, (long)TBL_P * 128, 1 /*bf16*/, 1 /*ssp*/, 1 /*mulC*/,
      (const unsigned short*)0, (const float*)0, (unsigned short*)0,
      TBL_P);

  k_h_init<<<(N * 32 + 255) / 256, 256, 0, stream>>>(
      (const float4*)emb, z, (float4*)h_buf, (ushort4*)hb, N);

  const int ngrid = (N + 63) / 64;
  const int wgrid = (N * 64 + 255) / 256;

  // initial hw = h0 @ aw_w[0] + aw_b[0]
  k_fused<<<dim3(ngrid, 1), 256, 0, stream>>>(
      hb, 0L,
      (const unsigned short*)0, 0L, (const float*)0, 0L,
      awt, 0L, aw_b, 0L,
      (const float*)0,
      hw, 0L, 1 /*bf16*/, 0, 0,
      (const unsigned short*)0, (const float*)0, (unsigned short*)0,
      N);

  for (int l = 0; l < L; ++l) {
    k_conv<<<wgrid, 256, 0, stream>>>(
        csr, ptr, T + (size_t)l * TBL_P * 128, hw, convb, N);
    const unsigned short* Wc = (l + 1 < L) ? (awt + (size_t)(l + 1) * 16384)
                                           : (const unsigned short*)0;
    const float* bc = (l + 1 < L) ? (aw_b + (size_t)(l + 1) * 128)
                                  : (const float*)0;
    k_fused<<<dim3(ngrid, 1), 256, 0, stream>>>(
        convb, 0L,
        o1t + (size_t)l * 16384, 0L, out_b1 + (size_t)l * 128, 0L,
        o2t + (size_t)l * 16384, 0L, out_b2 + (size_t)l * 128, 0L,
        h_buf,
        h_buf, 0L, 0 /*fp32*/, 0 /*no act*/, 0,
        Wc, bc, hw,
        N);
  }

  k_head<<<wgrid, 256, 0, stream>>>(
      h_buf, head_w1, head_b1, head_w2, head_b2, batch, (float*)d_out, N);
}

// Round 4
// 600.802 us; speedup vs baseline: 2.8023x; 1.0955x over previous
//
#include <hip/hip_runtime.h>
#include <math.h>

#define HID 128
#define NG_GAUSS 50
#define TBL_P 8192
#define TBL_DMAX 12.8f
#define TBL_DT (TBL_DMAX / (float)TBL_P)
#define TBL_INV_DT ((float)TBL_P / TBL_DMAX)
#define PI_F 3.14159265358979323846f

typedef short bf16x8 __attribute__((ext_vector_type(8)));
typedef float f32x4 __attribute__((ext_vector_type(4)));

__device__ __forceinline__ float ssp_f(float x) {
  return fmaxf(x, 0.f) + log1pf(expf(-fabsf(x))) - 0.69314718055994530942f;
}
__device__ __forceinline__ unsigned short f2bf(float x) {
  unsigned u = __float_as_uint(x);
  unsigned r = (u + 0x7FFFu + ((u >> 16) & 1u)) >> 16;
  return (unsigned short)r;
}

// ---------------- edge precompute: pack (row<<13 | i0), degree histogram ---
__global__ __launch_bounds__(256) void k_edge_pre(
    const float* __restrict__ pos, const int* __restrict__ ei,
    int E, int* __restrict__ epack, int* __restrict__ deg)
{
  int e = blockIdx.x * 256 + threadIdx.x;
  if (e >= E) return;
  int r = ei[e];
  int c = ei[E + e];
  float dx = pos[3*r+0] - pos[3*c+0];
  float dy = pos[3*r+1] - pos[3*c+1];
  float dz = pos[3*r+2] - pos[3*c+2];
  float d = sqrtf(dx*dx + dy*dy + dz*dz);
  int i0 = (int)(d * TBL_INV_DT + 0.5f);   // nearest table row
  if (i0 > TBL_P - 1) i0 = TBL_P - 1;      // rows >= 12.8A are exactly 0
  epack[e] = (r << 13) | i0;
  atomicAdd(&deg[c], 1);
}

// ---------------- exclusive scan over degrees (single block, 2-level) -----
__global__ __launch_bounds__(1024) void k_scan(
    const int* __restrict__ deg, int* __restrict__ ptr, int N)
{
  __shared__ int wsum[16];
  int t = threadIdx.x;
  int chunk = (N + 1023) / 1024;
  int b = t * chunk;
  int e2 = min(b + chunk, N);
  int s = 0;
  for (int i = b; i < e2; ++i) s += deg[i];
  int lane = t & 63, w = t >> 6;
  int ps = s;
  for (int o = 1; o < 64; o <<= 1) { int x = __shfl_up(ps, o); if (lane >= o) ps += x; }
  if (lane == 63) wsum[w] = ps;
  __syncthreads();
  if (w == 0 && lane < 16) {
    int v = wsum[lane];
    int pv = v;
    for (int o = 1; o < 16; o <<= 1) { int x = __shfl_up(pv, o); if (lane >= o) pv += x; }
    wsum[lane] = pv - v;  // exclusive
  }
  __syncthreads();
  int base = wsum[w] + ps - s;
  for (int i = b; i < e2; ++i) { ptr[i] = base; base += deg[i]; }
  if (t == 1023) ptr[N] = base;
}

// ---------------- scatter edges into CSR order ----------------------------
__global__ __launch_bounds__(256) void k_csr_scatter(
    const int* __restrict__ col, const int* __restrict__ epack,
    const int* __restrict__ ptr, int* __restrict__ cursor,
    int* __restrict__ csr, int E)
{
  int e = blockIdx.x * 256 + threadIdx.x;
  if (e >= E) return;
  int c = col[e];
  int slot = ptr[c] + atomicAdd(&cursor[c], 1);
  csr[slot] = epack[e];
}

// ---------------- weight prep: bf16, transposed [n][k], chunk-XOR swizzle -
__global__ __launch_bounds__(256) void k_wprep(
    const float* __restrict__ aw_w, const float* __restrict__ out_w1,
    const float* __restrict__ out_w2, const float* __restrict__ mlp_w2,
    const float* __restrict__ mlp_w1, const float* __restrict__ head_w1,
    unsigned short* __restrict__ awt, unsigned short* __restrict__ o1t,
    unsigned short* __restrict__ o2t, unsigned short* __restrict__ m2t,
    unsigned short* __restrict__ m1t, unsigned short* __restrict__ hwt)
{
  __shared__ float Wl[64][132];
  int l = blockIdx.x, t = blockIdx.y;
  const float* src; unsigned short* dst; int K; int NCOL = 128;
  switch (t) {
    case 0:  src = aw_w;   dst = awt; K = 128; break;
    case 1:  src = out_w1; dst = o1t; K = 128; break;
    case 2:  src = out_w2; dst = o2t; K = 128; break;
    case 3:  src = mlp_w2; dst = m2t; K = 128; break;
    case 4:  src = mlp_w1; dst = m1t; K = NG_GAUSS; break;
    default:
      if (l) return;
      src = head_w1; dst = hwt; K = 128; NCOL = 64; break;
  }
  src += (long)l * K * NCOL;
  dst += (long)l * 128 * 128;
  const int tid = threadIdx.x;
  for (int k0 = 0; k0 < 128; k0 += 64) {
    __syncthreads();
    for (int idx = tid; idx < 64 * 128; idx += 256) {
      int kk = idx >> 7, n = idx & 127;
      int k = k0 + kk;
      Wl[kk][n] = (k < K && n < NCOL) ? src[(long)k * NCOL + n] : 0.f;
    }
    __syncthreads();
    for (int idx = tid; idx < 128 * 8; idx += 256) {
      int n = idx >> 3, pl = idx & 7;
      int p = (k0 >> 3) + pl;          // stored chunk position
      int q = p ^ (n & 7);             // logical chunk (same 8-chunk half)
      int kk = (q << 3) - k0;
      ushort4 lo = make_ushort4(f2bf(Wl[kk+0][n]), f2bf(Wl[kk+1][n]),
                                f2bf(Wl[kk+2][n]), f2bf(Wl[kk+3][n]));
      ushort4 hi = make_ushort4(f2bf(Wl[kk+4][n]), f2bf(Wl[kk+5][n]),
                                f2bf(Wl[kk+6][n]), f2bf(Wl[kk+7][n]));
      *(ushort4*)(dst + ((long)n << 7) + (p << 3)) = lo;
      *(ushort4*)(dst + ((long)n << 7) + (p << 3) + 4) = hi;
    }
  }
}

// ---------------- gaussian feature table bf16 [TBL_P][128] zero-padded ----
__global__ void k_ea_build(unsigned short* __restrict__ EA)
{
  int p = blockIdx.x;
  int g = threadIdx.x; // 128 threads
  float v = 0.f;
  if (g < NG_GAUSS) {
    float step = 10.0f / 49.0f;
    float off = g * step;
    float coeff = -0.5f / (step * step);
    float t = p * TBL_DT - off;
    v = expf(coeff * t * t);
  }
  EA[p * 128 + g] = f2bf(v);
}

// ---------------- h init: h = emb[z] (fp32 + bf16 copy) -------------------
__global__ __launch_bounds__(256) void k_h_init(
    const float4* __restrict__ emb4, const int* __restrict__ z,
    float4* __restrict__ h4, ushort4* __restrict__ hb4, int N)
{
  int idx = blockIdx.x * 256 + threadIdx.x;
  if (idx >= N * 32) return;
  int n = idx >> 5, c = idx & 31;
  float4 v = emb4[z[n] * 32 + c];
  h4[idx] = v;
  hb4[idx] = make_ushort4(f2bf(v.x), f2bf(v.y), f2bf(v.z), f2bf(v.w));
}

// ---------------- fused GEMM chain ----------------------------------------
// Stage A (if Wa): tmp = ssp(X@Wa + ba)            (X bf16 [M][128])
// Stage B:         v = tmp@Wb + bb; [ssp]; [+R]; [*C(row*dscale)]; -> out1
// Stage C (if Wc): out2 = v_bf16@Wc + bc  (bf16)
// Weights pre-transposed/swizzled bf16 [128][128]. Batched over blockIdx.y.
__global__ __launch_bounds__(256) void k_fused(
    const unsigned short* __restrict__ X, long xstr,
    const unsigned short* __restrict__ Wa, long wastr,
    const float* __restrict__ ba, long bastr,
    const unsigned short* __restrict__ Wb, long wbstr,
    const float* __restrict__ bb, long bbstr,
    const float* __restrict__ R,
    void* __restrict__ out1, long o1str, int o1_bf16, int actB, int mulC,
    float dscale,
    const unsigned short* __restrict__ Wc, const float* __restrict__ bc,
    unsigned short* __restrict__ out2,
    int M)
{
  __shared__ unsigned short Xs[64][128];
  __shared__ unsigned short U[128][128];
  __shared__ unsigned short V[128][128];

  const int l = blockIdx.y;
  const int m0 = blockIdx.x * 64;
  const int tid = threadIdx.x;
  const unsigned short* Xb = X + (long)l * xstr;

  // stage X tile (bf16 16B chunks, XOR swizzle on chunk index)
  for (int idx = tid; idx < 1024; idx += 256) {
    int r = idx >> 4, c = idx & 15;
    int m = m0 + r;
    int4 v = make_int4(0, 0, 0, 0);
    if (m < M) v = *(const int4*)(Xb + (long)m * 128 + c * 8);
    *(int4*)&Xs[r][(c ^ (r & 7)) << 3] = v;
  }
  if (Wa) {
    const int4* s = (const int4*)(Wa + (long)l * wastr);
    int4* d = (int4*)U;
    for (int i = tid; i < 2048; i += 256) d[i] = s[i];
  }
  {
    const int4* s = (const int4*)(Wb + (long)l * wbstr);
    int4* d = (int4*)V;
    for (int i = tid; i < 2048; i += 256) d[i] = s[i];
  }
  __syncthreads();

  const int wv = tid >> 6, lane = tid & 63;
  const int lr = lane & 15, lk = lane >> 4;
  const int arow = (wv << 4) | lr;

  f32x4 acc[8];
  auto zacc = [&]() {
#pragma unroll
    for (int i = 0; i < 8; ++i)
#pragma unroll
      for (int j = 0; j < 4; ++j) acc[i][j] = 0.f;
  };
  auto gemm = [&](const unsigned short* Wl) {
#pragma unroll
    for (int kc = 0; kc < 4; ++kc) {
      int q = (kc << 2) | lk;
      bf16x8 a = *(const bf16x8*)&Xs[arow][(q ^ (arow & 7)) << 3];
#pragma unroll
      for (int nt = 0; nt < 8; ++nt) {
        int n = (nt << 4) | lr;
        bf16x8 b = *(const bf16x8*)(Wl + n * 128 + ((q ^ (n & 7)) << 3));
        acc[nt] = __builtin_amdgcn_mfma_f32_16x16x32_bf16(a, b, acc[nt], 0, 0, 0);
      }
    }
  };

  if (Wa) {
    const float* bab = ba + (long)l * bastr;
    zacc();
    gemm(&U[0][0]);
    __syncthreads();                   // all stage-A LDS reads done
#pragma unroll
    for (int nt = 0; nt < 8; ++nt) {
      int col = (nt << 4) | lr;
      float bv = bab[col];
#pragma unroll
      for (int r2 = 0; r2 < 4; ++r2) {
        int row = (wv << 4) | (lk << 2) | r2;
        float v2 = ssp_f(acc[nt][r2] + bv);
        int cch = col >> 3;
        Xs[row][((cch ^ (row & 7)) << 3) | (col & 7)] = f2bf(v2);
      }
    }
    if (Wc) {                          // refill U with Wc (read at stage C)
      const int4* s = (const int4*)Wc;
      int4* d = (int4*)U;
      for (int i = tid; i < 2048; i += 256) d[i] = s[i];
    }
    __syncthreads();
  }

  const float* bbb = bb + (long)l * bbstr;
  zacc();
  gemm(&V[0][0]);
  __syncthreads();                     // stage-B Xs reads done before overwrite

#pragma unroll
  for (int nt = 0; nt < 8; ++nt) {
    int col = (nt << 4) | lr;
    float bv = bbb[col];
#pragma unroll
    for (int r2 = 0; r2 < 4; ++r2) {
      int row = (wv << 4) | (lk << 2) | r2;
      int m = m0 + row;
      float v2 = acc[nt][r2] + bv;
      if (actB) v2 = ssp_f(v2);
      if (R && m < M) v2 += R[(long)m * 128 + col];
      if (mulC) {
        float d = (float)m * dscale;
        v2 *= 0.5f * (cosf(d * (PI_F / 10.0f)) + 1.0f);
      }
      if (m < M) {
        if (o1_bf16)
          ((unsigned short*)out1)[(long)l * o1str + (long)m * 128 + col] = f2bf(v2);
        else
          ((float*)out1)[(long)l * o1str + (long)m * 128 + col] = v2;
      }
      if (Wc) {
        int cch = col >> 3;
        Xs[row][((cch ^ (row & 7)) << 3) | (col & 7)] = f2bf(v2);
      }
    }
  }

  if (Wc) {
    __syncthreads();
    zacc();
    gemm(&U[0][0]);
#pragma unroll
    for (int nt = 0; nt < 8; ++nt) {
      int col = (nt << 4) | lr;
      float bv = bc[col];
#pragma unroll
      for (int r2 = 0; r2 < 4; ++r2) {
        int row = (wv << 4) | (lk << 2) | r2;
        int m = m0 + row;
        if (m < M)
          out2[(long)m * 128 + col] = f2bf(acc[nt][r2] + bv);
      }
    }
  }
}

// ---------------- conv: per-node gather, nearest-table, pipelined ---------
#define CONV_EDGE(PK, AX, AY) {                                              \
    unsigned pr = (unsigned)(PK);                                            \
    const unsigned short* t0 = T + ((size_t)(pr & 8191u) << 7) + (lane << 1);\
    unsigned tv = *(const unsigned*)t0;                                      \
    unsigned hv = *(const unsigned*)(hw + ((size_t)(pr >> 13) << 7) + (lane << 1)); \
    float w0 = __uint_as_float(tv << 16), w1 = __uint_as_float(tv & 0xffff0000u); \
    float h0 = __uint_as_float(hv << 16), h1 = __uint_as_float(hv & 0xffff0000u); \
    AX = fmaf(w0, h0, AX); AY = fmaf(w1, h1, AY); }

__global__ __launch_bounds__(256) void k_conv(
    const int* __restrict__ csr, const int* __restrict__ ptr,
    const unsigned short* __restrict__ T, const unsigned short* __restrict__ hw,
    unsigned short* __restrict__ convb, int N)
{
  int wid = (blockIdx.x * 256 + threadIdx.x) >> 6;
  int lane = threadIdx.x & 63;
  if (wid >= N) return;
  int s = ptr[wid], e = ptr[wid + 1];
  float ax0 = 0.f, ay0 = 0.f, ax1 = 0.f, ay1 = 0.f;
  float ax2 = 0.f, ay2 = 0.f, ax3 = 0.f, ay3 = 0.f;
  int j = s;
  if (j + 4 <= e) {
    int c0 = csr[j], c1 = csr[j + 1], c2 = csr[j + 2], c3 = csr[j + 3];
    for (; j + 8 <= e; j += 4) {
      int n0 = csr[j + 4], n1 = csr[j + 5], n2 = csr[j + 6], n3 = csr[j + 7];
      CONV_EDGE(c0, ax0, ay0);
      CONV_EDGE(c1, ax1, ay1);
      CONV_EDGE(c2, ax2, ay2);
      CONV_EDGE(c3, ax3, ay3);
      c0 = n0; c1 = n1; c2 = n2; c3 = n3;
    }
    CONV_EDGE(c0, ax0, ay0);
    CONV_EDGE(c1, ax1, ay1);
    CONV_EDGE(c2, ax2, ay2);
    CONV_EDGE(c3, ax3, ay3);
    j += 4;
  }
  for (; j < e; ++j) {
    int p = csr[j];
    CONV_EDGE(p, ax0, ay0);
  }
  float ax = (ax0 + ax1) + (ax2 + ax3);
  float ay = (ay0 + ay1) + (ay2 + ay3);
  unsigned outw = (unsigned)f2bf(ax) | ((unsigned)f2bf(ay) << 16);
  *(unsigned*)(convb + ((size_t)wid << 7) + (lane << 1)) = outw;
}

// ---------------- head: y = ssp(h@w1+b1)@w2+b2, segment-sum (MFMA) --------
__global__ __launch_bounds__(256) void k_head(
    const float* __restrict__ h, const unsigned short* __restrict__ w1t,
    const float* __restrict__ b1, const float* __restrict__ w2,
    const float* __restrict__ b2, const int* __restrict__ batch,
    float* __restrict__ out, int N)
{
  __shared__ unsigned short Xs[64][128];
  __shared__ unsigned short Wh[64][128];
  const int m0 = blockIdx.x * 64;
  const int tid = threadIdx.x;

  for (int idx = tid; idx < 1024; idx += 256) {
    int r = idx >> 4, c = idx & 15;
    int m = m0 + r;
    float4 lo = make_float4(0.f, 0.f, 0.f, 0.f), hi = lo;
    if (m < N) {
      lo = *(const float4*)&h[(long)m * 128 + c * 8];
      hi = *(const float4*)&h[(long)m * 128 + c * 8 + 4];
    }
    unsigned short* dstp = &Xs[r][(c ^ (r & 7)) << 3];
    *(ushort4*)dstp = make_ushort4(f2bf(lo.x), f2bf(lo.y), f2bf(lo.z), f2bf(lo.w));
    *(ushort4*)(dstp + 4) = make_ushort4(f2bf(hi.x), f2bf(hi.y), f2bf(hi.z), f2bf(hi.w));
  }
  {
    const int4* s = (const int4*)w1t;
    int4* d = (int4*)Wh;
    for (int i = tid; i < 1024; i += 256) d[i] = s[i];
  }
  __syncthreads();

  const int wv = tid >> 6, lane = tid & 63;
  const int lr = lane & 15, lk = lane >> 4;
  const int arow = (wv << 4) | lr;

  f32x4 acc[4];
#pragma unroll
  for (int i = 0; i < 4; ++i)
#pragma unroll
    for (int j2 = 0; j2 < 4; ++j2) acc[i][j2] = 0.f;

#pragma unroll
  for (int kc = 0; kc < 4; ++kc) {
    int q = (kc << 2) | lk;
    bf16x8 a = *(const bf16x8*)&Xs[arow][(q ^ (arow & 7)) << 3];
#pragma unroll
    for (int nt = 0; nt < 4; ++nt) {
      int n = (nt << 4) | lr;
      bf16x8 b = *(const bf16x8*)&Wh[n][(q ^ (n & 7)) << 3];
      acc[nt] = __builtin_amdgcn_mfma_f32_16x16x32_bf16(a, b, acc[nt], 0, 0, 0);
    }
  }

  float b1v[4], w2v[4];
#pragma unroll
  for (int nt = 0; nt < 4; ++nt) {
    int col = (nt << 4) | lr;
    b1v[nt] = b1[col];
    w2v[nt] = w2[col];
  }
  float bias2 = b2[0];
#pragma unroll
  for (int r2 = 0; r2 < 4; ++r2) {
    float sv = 0.f;
#pragma unroll
    for (int nt = 0; nt < 4; ++nt)
      sv += ssp_f(acc[nt][r2] + b1v[nt]) * w2v[nt];
    sv += __shfl_xor(sv, 1);
    sv += __shfl_xor(sv, 2);
    sv += __shfl_xor(sv, 4);
    sv += __shfl_xor(sv, 8);
    if (lr == 0) {
      int m = m0 + (wv << 4) + (lk << 2) + r2;
      if (m < N) atomicAdd(&out[batch[m]], sv + bias2);
    }
  }
}

extern "C" void kernel_launch(void* const* d_in, const int* in_sizes, int n_in,
                              void* d_out, int out_size, void* d_ws, size_t ws_size,
                              hipStream_t stream) {
  (void)n_in; (void)ws_size;
  const float* pos     = (const float*)d_in[0];
  const int*   z       = (const int*)d_in[1];
  const int*   batch   = (const int*)d_in[2];
  const int*   ei      = (const int*)d_in[3];
  const float* emb     = (const float*)d_in[4];
  const float* mlp_w1  = (const float*)d_in[5];
  const float* mlp_b1  = (const float*)d_in[6];
  const float* mlp_w2  = (const float*)d_in[7];
  const float* mlp_b2  = (const float*)d_in[8];
  const float* aw_w    = (const float*)d_in[9];
  const float* aw_b    = (const float*)d_in[10];
  const float* out_w1  = (const float*)d_in[11];
  const float* out_b1  = (const float*)d_in[12];
  const float* out_w2  = (const float*)d_in[13];
  const float* out_b2  = (const float*)d_in[14];
  const float* head_w1 = (const float*)d_in[15];
  const float* head_b1 = (const float*)d_in[16];
  const float* head_w2 = (const float*)d_in[17];
  const float* head_b2 = (const float*)d_in[18];

  const int N  = in_sizes[0] / 3;
  const int E  = in_sizes[3] / 2;
  const int NG = out_size;
  const int L  = in_sizes[5] / (NG_GAUSS * HID);

  char* ws = (char*)d_ws;
  size_t off = 0;
  auto alloc = [&](size_t bytes) -> void* {
    off = (off + 255) & ~(size_t)255;
    void* p = ws + off;
    off += bytes;
    return p;
  };

  const size_t nh = (size_t)N * HID;
  float* h_buf = (float*)alloc(nh * 4 > (size_t)E * 4 ? nh * 4 : (size_t)E * 4);
  int*   epack = (int*)h_buf;                   // alias (disjoint lifetime)
  unsigned short* hb    = (unsigned short*)alloc(nh * 2);
  unsigned short* hw    = (unsigned short*)alloc(nh * 2);
  unsigned short* convb = (unsigned short*)alloc(
      nh * 2 > (size_t)TBL_P * 128 * 2 ? nh * 2 : (size_t)TBL_P * 128 * 2);
  unsigned short* EA    = convb;                // alias (EA used pre-conv)
  int* csr = (int*)alloc((size_t)E * 4);
  unsigned short* T   = (unsigned short*)alloc((size_t)L * TBL_P * 128 * 2);
  unsigned short* awt = (unsigned short*)alloc((size_t)L * 16384 * 2);
  unsigned short* o1t = (unsigned short*)alloc((size_t)L * 16384 * 2);
  unsigned short* o2t = (unsigned short*)alloc((size_t)L * 16384 * 2);
  unsigned short* m2t = (unsigned short*)alloc((size_t)L * 16384 * 2);
  unsigned short* m1t = (unsigned short*)alloc((size_t)L * 16384 * 2);
  unsigned short* hwt = (unsigned short*)alloc((size_t)16384 * 2);
  int* deg    = (int*)alloc((size_t)N * 4);
  int* ptr    = (int*)alloc((size_t)(N + 1) * 4);
  int* cursor = (int*)alloc((size_t)N * 4);

  hipMemsetAsync(deg, 0, (size_t)N * 4, stream);
  hipMemsetAsync(cursor, 0, (size_t)N * 4, stream);
  hipMemsetAsync(d_out, 0, (size_t)NG * 4, stream);

  int egrid = (E + 255) / 256;
  k_edge_pre<<<egrid, 256, 0, stream>>>(pos, ei, E, epack, deg);
  k_scan<<<1, 1024, 0, stream>>>(deg, ptr, N);
  k_csr_scatter<<<egrid, 256, 0, stream>>>(ei + E, epack, ptr, cursor, csr, E);

  k_wprep<<<dim3(L, 6), 256, 0, stream>>>(aw_w, out_w1, out_w2, mlp_w2, mlp_w1,
                                          head_w1, awt, o1t, o2t, m2t, m1t, hwt);
  k_ea_build<<<TBL_P, 128, 0, stream>>>(EA);

  // filter tables: T_l = ssp(ssp(EA@w1+b1)@w2+b2) * C(d), bf16, batched
  k_fused<<<dim3(TBL_P / 64, L), 256, 0, stream>>>(
      EA, 0L,
      m1t, 16384L, mlp_b1, 128L,
      m2t, 16384L, mlp_b2, 128L,
      (const float*)0,
      T, (long)TBL_P * 128, 1 /*bf16*/, 1 /*ssp*/, 1 /*mulC*/, TBL_DT,
      (const unsigned short*)0, (const float*)0, (unsigned short*)0,
      TBL_P);

  k_h_init<<<(N * 32 + 255) / 256, 256, 0, stream>>>(
      (const float4*)emb, z, (float4*)h_buf, (ushort4*)hb, N);

  const int ngrid = (N + 63) / 64;
  const int wgrid = (N * 64 + 255) / 256;

  // initial hw = h0 @ aw_w[0] + aw_b[0]
  k_fused<<<dim3(ngrid, 1), 256, 0, stream>>>(
      hb, 0L,
      (const unsigned short*)0, 0L, (const float*)0, 0L,
      awt, 0L, aw_b, 0L,
      (const float*)0,
      hw, 0L, 1 /*bf16*/, 0, 0, 0.f,
      (const unsigned short*)0, (const float*)0, (unsigned short*)0,
      N);

  for (int l = 0; l < L; ++l) {
    k_conv<<<wgrid, 256, 0, stream>>>(
        csr, ptr, T + (size_t)l * TBL_P * 128, hw, convb, N);
    const unsigned short* Wc = (l + 1 < L) ? (awt + (size_t)(l + 1) * 16384)
                                           : (const unsigned short*)0;
    const float* bc = (l + 1 < L) ? (aw_b + (size_t)(l + 1) * 128)
                                  : (const float*)0;
    k_fused<<<dim3(ngrid, 1), 256, 0, stream>>>(
        convb, 0L,
        o1t + (size_t)l * 16384, 0L, out_b1 + (size_t)l * 128, 0L,
        o2t + (size_t)l * 16384, 0L, out_b2 + (size_t)l * 128, 0L,
        h_buf,
        h_buf, 0L, 0 /*fp32*/, 0 /*no act*/, 0, 0.f,
        Wc, bc, hw,
        N);
  }

  k_head<<<ngrid, 256, 0, stream>>>(
      h_buf, hwt, head_b1, head_w2, head_b2, batch, (float*)d_out, N);
}

// Round 5
// 507.382 us; speedup vs baseline: 3.3183x; 1.1841x over previous
//
#include <hip/hip_runtime.h>
#include <math.h>

#define HID 128
#define NG_GAUSS 50
#define TBL_P 8192
#define TBL_DMAX 12.8f
#define TBL_DT (TBL_DMAX / (float)TBL_P)
#define TBL_INV_DT ((float)TBL_P / TBL_DMAX)
#define PI_F 3.14159265358979323846f

typedef short bf16x8 __attribute__((ext_vector_type(8)));
typedef float f32x4 __attribute__((ext_vector_type(4)));

// fast shifted-softplus via HW transcendentals (v_exp_f32 / v_log_f32)
__device__ __forceinline__ float ssp_f(float x) {
  float e = __expf(-fabsf(x));
  return fmaxf(x, 0.f) + __logf(1.f + e) - 0.69314718055994530942f;
}
__device__ __forceinline__ unsigned short f2bf(float x) {
  unsigned u = __float_as_uint(x);
  unsigned r = (u + 0x7FFFu + ((u >> 16) & 1u)) >> 16;
  return (unsigned short)r;
}

// ---------------- edge precompute: pack (row<<13 | i0), degree histogram ---
__global__ __launch_bounds__(256) void k_edge_pre(
    const float* __restrict__ pos, const int* __restrict__ ei,
    int E, int* __restrict__ epack, int* __restrict__ deg)
{
  int e = blockIdx.x * 256 + threadIdx.x;
  if (e >= E) return;
  int r = ei[e];
  int c = ei[E + e];
  float dx = pos[3*r+0] - pos[3*c+0];
  float dy = pos[3*r+1] - pos[3*c+1];
  float dz = pos[3*r+2] - pos[3*c+2];
  float d = sqrtf(dx*dx + dy*dy + dz*dz);
  int i0 = (int)(d * TBL_INV_DT + 0.5f);   // nearest table row
  if (i0 > TBL_P - 1) i0 = TBL_P - 1;      // rows >= 12.8A are exactly 0
  epack[e] = (r << 13) | i0;
  atomicAdd(&deg[c], 1);
}

// ---------------- exclusive scan over degrees (single block, 2-level) -----
__global__ __launch_bounds__(1024) void k_scan(
    const int* __restrict__ deg, int* __restrict__ ptr, int N)
{
  __shared__ int wsum[16];
  int t = threadIdx.x;
  int chunk = (N + 1023) / 1024;
  int b = t * chunk;
  int e2 = min(b + chunk, N);
  int s = 0;
  for (int i = b; i < e2; ++i) s += deg[i];
  int lane = t & 63, w = t >> 6;
  int ps = s;
  for (int o = 1; o < 64; o <<= 1) { int x = __shfl_up(ps, o); if (lane >= o) ps += x; }
  if (lane == 63) wsum[w] = ps;
  __syncthreads();
  if (w == 0 && lane < 16) {
    int v = wsum[lane];
    int pv = v;
    for (int o = 1; o < 16; o <<= 1) { int x = __shfl_up(pv, o); if (lane >= o) pv += x; }
    wsum[lane] = pv - v;  // exclusive
  }
  __syncthreads();
  int base = wsum[w] + ps - s;
  for (int i = b; i < e2; ++i) { ptr[i] = base; base += deg[i]; }
  if (t == 1023) ptr[N] = base;
}

// ---------------- scatter edges into CSR order ----------------------------
__global__ __launch_bounds__(256) void k_csr_scatter(
    const int* __restrict__ col, const int* __restrict__ epack,
    const int* __restrict__ ptr, int* __restrict__ cursor,
    int* __restrict__ csr, int E)
{
  int e = blockIdx.x * 256 + threadIdx.x;
  if (e >= E) return;
  int c = col[e];
  int slot = ptr[c] + atomicAdd(&cursor[c], 1);
  csr[slot] = epack[e];
}

// ---------------- weight prep: bf16, transposed [n][k], chunk-XOR swizzle -
__global__ __launch_bounds__(256) void k_wprep(
    const float* __restrict__ aw_w, const float* __restrict__ out_w1,
    const float* __restrict__ out_w2, const float* __restrict__ mlp_w2,
    const float* __restrict__ mlp_w1, const float* __restrict__ head_w1,
    unsigned short* __restrict__ awt, unsigned short* __restrict__ o1t,
    unsigned short* __restrict__ o2t, unsigned short* __restrict__ m2t,
    unsigned short* __restrict__ m1t, unsigned short* __restrict__ hwt)
{
  __shared__ float Wl[64][132];
  int l = blockIdx.x, t = blockIdx.y;
  const float* src; unsigned short* dst; int K; int NCOL = 128;
  switch (t) {
    case 0:  src = aw_w;   dst = awt; K = 128; break;
    case 1:  src = out_w1; dst = o1t; K = 128; break;
    case 2:  src = out_w2; dst = o2t; K = 128; break;
    case 3:  src = mlp_w2; dst = m2t; K = 128; break;
    case 4:  src = mlp_w1; dst = m1t; K = NG_GAUSS; break;
    default:
      if (l) return;
      src = head_w1; dst = hwt; K = 128; NCOL = 64; break;
  }
  src += (long)l * K * NCOL;
  dst += (long)l * 128 * 128;
  const int tid = threadIdx.x;
  for (int k0 = 0; k0 < 128; k0 += 64) {
    __syncthreads();
    for (int idx = tid; idx < 64 * 128; idx += 256) {
      int kk = idx >> 7, n = idx & 127;
      int k = k0 + kk;
      Wl[kk][n] = (k < K && n < NCOL) ? src[(long)k * NCOL + n] : 0.f;
    }
    __syncthreads();
    for (int idx = tid; idx < 128 * 8; idx += 256) {
      int n = idx >> 3, pl = idx & 7;
      int p = (k0 >> 3) + pl;          // stored chunk position
      int q = p ^ (n & 7);             // logical chunk (same 8-chunk half)
      int kk = (q << 3) - k0;
      ushort4 lo = make_ushort4(f2bf(Wl[kk+0][n]), f2bf(Wl[kk+1][n]),
                                f2bf(Wl[kk+2][n]), f2bf(Wl[kk+3][n]));
      ushort4 hi = make_ushort4(f2bf(Wl[kk+4][n]), f2bf(Wl[kk+5][n]),
                                f2bf(Wl[kk+6][n]), f2bf(Wl[kk+7][n]));
      *(ushort4*)(dst + ((long)n << 7) + (p << 3)) = lo;
      *(ushort4*)(dst + ((long)n << 7) + (p << 3) + 4) = hi;
    }
  }
}

// ---------------- gaussian feature table bf16 [TBL_P][128] zero-padded ----
__global__ void k_ea_build(unsigned short* __restrict__ EA)
{
  int p = blockIdx.x;
  int g = threadIdx.x; // 128 threads
  float v = 0.f;
  if (g < NG_GAUSS) {
    float step = 10.0f / 49.0f;
    float off = g * step;
    float coeff = -0.5f / (step * step);
    float t = p * TBL_DT - off;
    v = __expf(coeff * t * t);
  }
  EA[p * 128 + g] = f2bf(v);
}

// ---------------- h init: h = emb[z] (fp32 + bf16 copy) -------------------
__global__ __launch_bounds__(256) void k_h_init(
    const float4* __restrict__ emb4, const int* __restrict__ z,
    float4* __restrict__ h4, ushort4* __restrict__ hb4, int N)
{
  int idx = blockIdx.x * 256 + threadIdx.x;
  if (idx >= N * 32) return;
  int n = idx >> 5, c = idx & 31;
  float4 v = emb4[z[n] * 32 + c];
  h4[idx] = v;
  hb4[idx] = make_ushort4(f2bf(v.x), f2bf(v.y), f2bf(v.z), f2bf(v.w));
}

// ---------------- fused GEMM chain ----------------------------------------
// Stage A (if Wa): tmp = ssp(X@Wa + ba)            (X bf16 [M][128])
// Stage B:         v = tmp@Wb + bb; [ssp]; [+R]; [*C(row*dscale)]; -> out1?
// Stage C (if Wc): out2 = v_bf16@Wc + bc  (bf16)
//   head mode (hw2!=0): per-row ssp(acc+bc)*hw2 -> reduce -> atomicAdd(outp)
// Weights pre-transposed/swizzled bf16 [128][128]. Batched over blockIdx.y.
__global__ __launch_bounds__(256) void k_fused(
    const unsigned short* __restrict__ X, long xstr,
    const unsigned short* __restrict__ Wa, long wastr,
    const float* __restrict__ ba, long bastr,
    const unsigned short* __restrict__ Wb, long wbstr,
    const float* __restrict__ bb, long bbstr,
    const float* __restrict__ R,
    void* __restrict__ out1, long o1str, int o1_bf16, int actB, int mulC,
    float dscale,
    const unsigned short* __restrict__ Wc, const float* __restrict__ bc,
    unsigned short* __restrict__ out2,
    const float* __restrict__ hw2, const float* __restrict__ hb2,
    const int* __restrict__ batchp, float* __restrict__ outp,
    int M)
{
  __shared__ unsigned short Xs[64][128];
  __shared__ unsigned short U[128][128];
  __shared__ unsigned short V[128][128];

  const int l = blockIdx.y;
  const int m0 = blockIdx.x * 64;
  const int tid = threadIdx.x;
  const unsigned short* Xb = X + (long)l * xstr;

  // stage X tile (bf16 16B chunks, XOR swizzle on chunk index)
  for (int idx = tid; idx < 1024; idx += 256) {
    int r = idx >> 4, c = idx & 15;
    int m = m0 + r;
    int4 v = make_int4(0, 0, 0, 0);
    if (m < M) v = *(const int4*)(Xb + (long)m * 128 + c * 8);
    *(int4*)&Xs[r][(c ^ (r & 7)) << 3] = v;
  }
  if (Wa) {
    const int4* s = (const int4*)(Wa + (long)l * wastr);
    int4* d = (int4*)U;
    for (int i = tid; i < 2048; i += 256) d[i] = s[i];
  }
  {
    const int4* s = (const int4*)(Wb + (long)l * wbstr);
    int4* d = (int4*)V;
    for (int i = tid; i < 2048; i += 256) d[i] = s[i];
  }
  __syncthreads();

  const int wv = tid >> 6, lane = tid & 63;
  const int lr = lane & 15, lk = lane >> 4;
  const int arow = (wv << 4) | lr;

  f32x4 acc[8];
  auto zacc = [&]() {
#pragma unroll
    for (int i = 0; i < 8; ++i)
#pragma unroll
      for (int j = 0; j < 4; ++j) acc[i][j] = 0.f;
  };
  auto gemm = [&](const unsigned short* Wl) {
#pragma unroll
    for (int kc = 0; kc < 4; ++kc) {
      int q = (kc << 2) | lk;
      bf16x8 a = *(const bf16x8*)&Xs[arow][(q ^ (arow & 7)) << 3];
#pragma unroll
      for (int nt = 0; nt < 8; ++nt) {
        int n = (nt << 4) | lr;
        bf16x8 b = *(const bf16x8*)(Wl + n * 128 + ((q ^ (n & 7)) << 3));
        acc[nt] = __builtin_amdgcn_mfma_f32_16x16x32_bf16(a, b, acc[nt], 0, 0, 0);
      }
    }
  };

  if (Wa) {
    const float* bab = ba + (long)l * bastr;
    zacc();
    gemm(&U[0][0]);
    __syncthreads();                   // all stage-A LDS reads done
#pragma unroll
    for (int nt = 0; nt < 8; ++nt) {
      int col = (nt << 4) | lr;
      float bv = bab[col];
#pragma unroll
      for (int r2 = 0; r2 < 4; ++r2) {
        int row = (wv << 4) | (lk << 2) | r2;
        float v2 = ssp_f(acc[nt][r2] + bv);
        int cch = col >> 3;
        Xs[row][((cch ^ (row & 7)) << 3) | (col & 7)] = f2bf(v2);
      }
    }
    if (Wc) {                          // refill U with Wc (read at stage C)
      const int4* s = (const int4*)Wc;
      int4* d = (int4*)U;
      for (int i = tid; i < 2048; i += 256) d[i] = s[i];
    }
    __syncthreads();
  }

  const float* bbb = bb + (long)l * bbstr;
  zacc();
  gemm(&V[0][0]);
  __syncthreads();                     // stage-B Xs reads done before overwrite

#pragma unroll
  for (int nt = 0; nt < 8; ++nt) {
    int col = (nt << 4) | lr;
    float bv = bbb[col];
#pragma unroll
    for (int r2 = 0; r2 < 4; ++r2) {
      int row = (wv << 4) | (lk << 2) | r2;
      int m = m0 + row;
      float v2 = acc[nt][r2] + bv;
      if (actB) v2 = ssp_f(v2);
      if (R && m < M) v2 += R[(long)m * 128 + col];
      if (mulC) {
        float d = (float)m * dscale;
        v2 *= 0.5f * (__cosf(d * (PI_F / 10.0f)) + 1.0f);
      }
      if (m < M && out1) {
        if (o1_bf16)
          ((unsigned short*)out1)[(long)l * o1str + (long)m * 128 + col] = f2bf(v2);
        else
          ((float*)out1)[(long)l * o1str + (long)m * 128 + col] = v2;
      }
      if (Wc) {
        int cch = col >> 3;
        Xs[row][((cch ^ (row & 7)) << 3) | (col & 7)] = f2bf(v2);
      }
    }
  }

  if (Wc) {
    __syncthreads();
    zacc();
    gemm(&U[0][0]);
    if (hw2) {
      // fused head: y = ssp(v@Wc + bc) . hw2 + hb2, segment-sum by batch
      float b1v[4], w2v[4];
#pragma unroll
      for (int nt = 0; nt < 4; ++nt) {
        int col = (nt << 4) | lr;
        b1v[nt] = bc[col];
        w2v[nt] = hw2[col];
      }
      float bias2 = hb2[0];
#pragma unroll
      for (int r2 = 0; r2 < 4; ++r2) {
        float sv = 0.f;
#pragma unroll
        for (int nt = 0; nt < 4; ++nt)
          sv += ssp_f(acc[nt][r2] + b1v[nt]) * w2v[nt];
        sv += __shfl_xor(sv, 1);
        sv += __shfl_xor(sv, 2);
        sv += __shfl_xor(sv, 4);
        sv += __shfl_xor(sv, 8);
        if (lr == 0) {
          int m = m0 + (wv << 4) + (lk << 2) + r2;
          if (m < M) atomicAdd(&outp[batchp[m]], sv + bias2);
        }
      }
    } else {
#pragma unroll
      for (int nt = 0; nt < 8; ++nt) {
        int col = (nt << 4) | lr;
        float bv = bc[col];
#pragma unroll
        for (int r2 = 0; r2 < 4; ++r2) {
          int row = (wv << 4) | (lk << 2) | r2;
          int m = m0 + row;
          if (m < M)
            out2[(long)m * 128 + col] = f2bf(acc[nt][r2] + bv);
        }
      }
    }
  }
}

// ---------------- conv: per-node gather, nearest-table, pipelined ---------
#define CONV_EDGE(PK, AX, AY) {                                              \
    unsigned pr = (unsigned)(PK);                                            \
    const unsigned short* t0 = T + ((size_t)(pr & 8191u) << 7) + (lane << 1);\
    unsigned tv = *(const unsigned*)t0;                                      \
    unsigned hv = *(const unsigned*)(hw + ((size_t)(pr >> 13) << 7) + (lane << 1)); \
    float w0 = __uint_as_float(tv << 16), w1 = __uint_as_float(tv & 0xffff0000u); \
    float h0 = __uint_as_float(hv << 16), h1 = __uint_as_float(hv & 0xffff0000u); \
    AX = fmaf(w0, h0, AX); AY = fmaf(w1, h1, AY); }

__global__ __launch_bounds__(256) void k_conv(
    const int* __restrict__ csr, const int* __restrict__ ptr,
    const unsigned short* __restrict__ T, const unsigned short* __restrict__ hw,
    unsigned short* __restrict__ convb, int N)
{
  int wid = (blockIdx.x * 256 + threadIdx.x) >> 6;
  int lane = threadIdx.x & 63;
  if (wid >= N) return;
  int s = ptr[wid], e = ptr[wid + 1];
  float ax0 = 0.f, ay0 = 0.f, ax1 = 0.f, ay1 = 0.f;
  float ax2 = 0.f, ay2 = 0.f, ax3 = 0.f, ay3 = 0.f;
  int j = s;
  if (j + 4 <= e) {
    int c0 = csr[j], c1 = csr[j + 1], c2 = csr[j + 2], c3 = csr[j + 3];
    for (; j + 8 <= e; j += 4) {
      int n0 = csr[j + 4], n1 = csr[j + 5], n2 = csr[j + 6], n3 = csr[j + 7];
      CONV_EDGE(c0, ax0, ay0);
      CONV_EDGE(c1, ax1, ay1);
      CONV_EDGE(c2, ax2, ay2);
      CONV_EDGE(c3, ax3, ay3);
      c0 = n0; c1 = n1; c2 = n2; c3 = n3;
    }
    CONV_EDGE(c0, ax0, ay0);
    CONV_EDGE(c1, ax1, ay1);
    CONV_EDGE(c2, ax2, ay2);
    CONV_EDGE(c3, ax3, ay3);
    j += 4;
  }
  for (; j < e; ++j) {
    int p = csr[j];
    CONV_EDGE(p, ax0, ay0);
  }
  float ax = (ax0 + ax1) + (ax2 + ax3);
  float ay = (ay0 + ay1) + (ay2 + ay3);
  unsigned outw = (unsigned)f2bf(ax) | ((unsigned)f2bf(ay) << 16);
  *(unsigned*)(convb + ((size_t)wid << 7) + (lane << 1)) = outw;
}

extern "C" void kernel_launch(void* const* d_in, const int* in_sizes, int n_in,
                              void* d_out, int out_size, void* d_ws, size_t ws_size,
                              hipStream_t stream) {
  (void)n_in; (void)ws_size;
  const float* pos     = (const float*)d_in[0];
  const int*   z       = (const int*)d_in[1];
  const int*   batch   = (const int*)d_in[2];
  const int*   ei      = (const int*)d_in[3];
  const float* emb     = (const float*)d_in[4];
  const float* mlp_w1  = (const float*)d_in[5];
  const float* mlp_b1  = (const float*)d_in[6];
  const float* mlp_w2  = (const float*)d_in[7];
  const float* mlp_b2  = (const float*)d_in[8];
  const float* aw_w    = (const float*)d_in[9];
  const float* aw_b    = (const float*)d_in[10];
  const float* out_w1  = (const float*)d_in[11];
  const float* out_b1  = (const float*)d_in[12];
  const float* out_w2  = (const float*)d_in[13];
  const float* out_b2  = (const float*)d_in[14];
  const float* head_w1 = (const float*)d_in[15];
  const float* head_b1 = (const float*)d_in[16];
  const float* head_w2 = (const float*)d_in[17];
  const float* head_b2 = (const float*)d_in[18];

  const int N  = in_sizes[0] / 3;
  const int E  = in_sizes[3] / 2;
  const int NG = out_size;
  const int L  = in_sizes[5] / (NG_GAUSS * HID);

  char* ws = (char*)d_ws;
  size_t off = 0;
  auto alloc = [&](size_t bytes) -> void* {
    off = (off + 255) & ~(size_t)255;
    void* p = ws + off;
    off += bytes;
    return p;
  };

  const size_t nh = (size_t)N * HID;
  float* h_buf = (float*)alloc(nh * 4 > (size_t)E * 4 ? nh * 4 : (size_t)E * 4);
  int*   epack = (int*)h_buf;                   // alias (disjoint lifetime)
  unsigned short* hb    = (unsigned short*)alloc(nh * 2);
  unsigned short* hw    = (unsigned short*)alloc(nh * 2);
  unsigned short* convb = (unsigned short*)alloc(
      nh * 2 > (size_t)TBL_P * 128 * 2 ? nh * 2 : (size_t)TBL_P * 128 * 2);
  unsigned short* EA    = convb;                // alias (EA used pre-conv)
  int* csr = (int*)alloc((size_t)E * 4);
  unsigned short* T   = (unsigned short*)alloc((size_t)L * TBL_P * 128 * 2);
  unsigned short* awt = (unsigned short*)alloc((size_t)L * 16384 * 2);
  unsigned short* o1t = (unsigned short*)alloc((size_t)L * 16384 * 2);
  unsigned short* o2t = (unsigned short*)alloc((size_t)L * 16384 * 2);
  unsigned short* m2t = (unsigned short*)alloc((size_t)L * 16384 * 2);
  unsigned short* m1t = (unsigned short*)alloc((size_t)L * 16384 * 2);
  unsigned short* hwt = (unsigned short*)alloc((size_t)16384 * 2);
  int* deg    = (int*)alloc((size_t)N * 4);
  int* ptr    = (int*)alloc((size_t)(N + 1) * 4);
  int* cursor = (int*)alloc((size_t)N * 4);

  hipMemsetAsync(deg, 0, (size_t)N * 4, stream);
  hipMemsetAsync(cursor, 0, (size_t)N * 4, stream);
  hipMemsetAsync(d_out, 0, (size_t)NG * 4, stream);

  int egrid = (E + 255) / 256;
  k_edge_pre<<<egrid, 256, 0, stream>>>(pos, ei, E, epack, deg);
  k_scan<<<1, 1024, 0, stream>>>(deg, ptr, N);
  k_csr_scatter<<<egrid, 256, 0, stream>>>(ei + E, epack, ptr, cursor, csr, E);

  k_wprep<<<dim3(L, 6), 256, 0, stream>>>(aw_w, out_w1, out_w2, mlp_w2, mlp_w1,
                                          head_w1, awt, o1t, o2t, m2t, m1t, hwt);
  k_ea_build<<<TBL_P, 128, 0, stream>>>(EA);

  // filter tables: T_l = ssp(ssp(EA@w1+b1)@w2+b2) * C(d), bf16, batched
  k_fused<<<dim3(TBL_P / 64, L), 256, 0, stream>>>(
      EA, 0L,
      m1t, 16384L, mlp_b1, 128L,
      m2t, 16384L, mlp_b2, 128L,
      (const float*)0,
      T, (long)TBL_P * 128, 1 /*bf16*/, 1 /*ssp*/, 1 /*mulC*/, TBL_DT,
      (const unsigned short*)0, (const float*)0, (unsigned short*)0,
      (const float*)0, (const float*)0, (const int*)0, (float*)0,
      TBL_P);

  k_h_init<<<(N * 32 + 255) / 256, 256, 0, stream>>>(
      (const float4*)emb, z, (float4*)h_buf, (ushort4*)hb, N);

  const int ngrid = (N + 63) / 64;
  const int wgrid = (N * 64 + 255) / 256;

  // initial hw = h0 @ aw_w[0] + aw_b[0]
  k_fused<<<dim3(ngrid, 1), 256, 0, stream>>>(
      hb, 0L,
      (const unsigned short*)0, 0L, (const float*)0, 0L,
      awt, 0L, aw_b, 0L,
      (const float*)0,
      hw, 0L, 1 /*bf16*/, 0, 0, 0.f,
      (const unsigned short*)0, (const float*)0, (unsigned short*)0,
      (const float*)0, (const float*)0, (const int*)0, (float*)0,
      N);

  for (int l = 0; l < L; ++l) {
    k_conv<<<wgrid, 256, 0, stream>>>(
        csr, ptr, T + (size_t)l * TBL_P * 128, hw, convb, N);
    const int last = (l + 1 == L);
    const unsigned short* Wc = last ? hwt : (awt + (size_t)(l + 1) * 16384);
    const float* bc = last ? head_b1 : (aw_b + (size_t)(l + 1) * 128);
    k_fused<<<dim3(ngrid, 1), 256, 0, stream>>>(
        convb, 0L,
        o1t + (size_t)l * 16384, 0L, out_b1 + (size_t)l * 128, 0L,
        o2t + (size_t)l * 16384, 0L, out_b2 + (size_t)l * 128, 0L,
        h_buf,
        last ? (void*)0 : (void*)h_buf, 0L, 0 /*fp32*/, 0 /*no act*/, 0, 0.f,
        Wc, bc, last ? (unsigned short*)0 : hw,
        last ? head_w2 : (const float*)0, last ? head_b2 : (const float*)0,
        last ? batch : (const int*)0, last ? (float*)d_out : (float*)0,
        N);
  }
}

// Round 6
// 506.844 us; speedup vs baseline: 3.3218x; 1.0011x over previous
//
#include <hip/hip_runtime.h>
#include <math.h>

#define HID 128
#define NG_GAUSS 50
#define TBL_P 8192
#define TBL_DMAX 12.8f
#define TBL_DT (TBL_DMAX / (float)TBL_P)
#define TBL_INV_DT ((float)TBL_P / TBL_DMAX)
#define PI_F 3.14159265358979323846f

typedef short bf16x8 __attribute__((ext_vector_type(8)));
typedef float f32x4 __attribute__((ext_vector_type(4)));

// fast shifted-softplus via HW transcendentals (v_exp_f32 / v_log_f32)
__device__ __forceinline__ float ssp_f(float x) {
  float e = __expf(-fabsf(x));
  return fmaxf(x, 0.f) + __logf(1.f + e) - 0.69314718055994530942f;
}
__device__ __forceinline__ unsigned short f2bf(float x) {
  unsigned u = __float_as_uint(x);
  unsigned r = (u + 0x7FFFu + ((u >> 16) & 1u)) >> 16;
  return (unsigned short)r;
}

// ---------------- edge precompute: pack (row<<13 | i0), degree histogram ---
__global__ __launch_bounds__(256) void k_edge_pre(
    const float* __restrict__ pos, const int* __restrict__ ei,
    int E, int* __restrict__ epack, int* __restrict__ deg)
{
  int e = blockIdx.x * 256 + threadIdx.x;
  if (e >= E) return;
  int r = ei[e];
  int c = ei[E + e];
  float dx = pos[3*r+0] - pos[3*c+0];
  float dy = pos[3*r+1] - pos[3*c+1];
  float dz = pos[3*r+2] - pos[3*c+2];
  float d = sqrtf(dx*dx + dy*dy + dz*dz);
  int i0 = (int)(d * TBL_INV_DT + 0.5f);   // nearest table row
  if (i0 > TBL_P - 1) i0 = TBL_P - 1;      // rows >= 12.8A give exactly 0
  epack[e] = (r << 13) | i0;
  atomicAdd(&deg[c], 1);
}

// ---------------- exclusive scan over degrees (single block, 2-level) -----
__global__ __launch_bounds__(1024) void k_scan(
    const int* __restrict__ deg, int* __restrict__ ptr, int N)
{
  __shared__ int wsum[16];
  int t = threadIdx.x;
  int chunk = (N + 1023) / 1024;
  int b = t * chunk;
  int e2 = min(b + chunk, N);
  int s = 0;
  for (int i = b; i < e2; ++i) s += deg[i];
  int lane = t & 63, w = t >> 6;
  int ps = s;
  for (int o = 1; o < 64; o <<= 1) { int x = __shfl_up(ps, o); if (lane >= o) ps += x; }
  if (lane == 63) wsum[w] = ps;
  __syncthreads();
  if (w == 0 && lane < 16) {
    int v = wsum[lane];
    int pv = v;
    for (int o = 1; o < 16; o <<= 1) { int x = __shfl_up(pv, o); if (lane >= o) pv += x; }
    wsum[lane] = pv - v;  // exclusive
  }
  __syncthreads();
  int base = wsum[w] + ps - s;
  for (int i = b; i < e2; ++i) { ptr[i] = base; base += deg[i]; }
  if (t == 1023) ptr[N] = base;
}

// ---------------- scatter edges into CSR order ----------------------------
__global__ __launch_bounds__(256) void k_csr_scatter(
    const int* __restrict__ col, const int* __restrict__ epack,
    const int* __restrict__ ptr, int* __restrict__ cursor,
    int* __restrict__ csr, int E)
{
  int e = blockIdx.x * 256 + threadIdx.x;
  if (e >= E) return;
  int c = col[e];
  int slot = ptr[c] + atomicAdd(&cursor[c], 1);
  csr[slot] = epack[e];
}

// ---------------- weight prep: bf16, transposed [n][k], chunk-XOR swizzle -
__global__ __launch_bounds__(256) void k_wprep(
    const float* __restrict__ aw_w, const float* __restrict__ out_w1,
    const float* __restrict__ out_w2, const float* __restrict__ mlp_w2,
    const float* __restrict__ mlp_w1, const float* __restrict__ head_w1,
    unsigned short* __restrict__ awt, unsigned short* __restrict__ o1t,
    unsigned short* __restrict__ o2t, unsigned short* __restrict__ m2t,
    unsigned short* __restrict__ m1t, unsigned short* __restrict__ hwt)
{
  __shared__ float Wl[64][132];
  int l = blockIdx.x, t = blockIdx.y;
  const float* src; unsigned short* dst; int K; int NCOL = 128;
  switch (t) {
    case 0:  src = aw_w;   dst = awt; K = 128; break;
    case 1:  src = out_w1; dst = o1t; K = 128; break;
    case 2:  src = out_w2; dst = o2t; K = 128; break;
    case 3:  src = mlp_w2; dst = m2t; K = 128; break;
    case 4:  src = mlp_w1; dst = m1t; K = NG_GAUSS; break;
    default:
      if (l) return;
      src = head_w1; dst = hwt; K = 128; NCOL = 64; break;
  }
  src += (long)l * K * NCOL;
  dst += (long)l * 128 * 128;
  const int tid = threadIdx.x;
  for (int k0 = 0; k0 < 128; k0 += 64) {
    __syncthreads();
    for (int idx = tid; idx < 64 * 128; idx += 256) {
      int kk = idx >> 7, n = idx & 127;
      int k = k0 + kk;
      Wl[kk][n] = (k < K && n < NCOL) ? src[(long)k * NCOL + n] : 0.f;
    }
    __syncthreads();
    for (int idx = tid; idx < 128 * 8; idx += 256) {
      int n = idx >> 3, pl = idx & 7;
      int p = (k0 >> 3) + pl;          // stored chunk position
      int q = p ^ (n & 7);             // logical chunk (same 8-chunk half)
      int kk = (q << 3) - k0;
      ushort4 lo = make_ushort4(f2bf(Wl[kk+0][n]), f2bf(Wl[kk+1][n]),
                                f2bf(Wl[kk+2][n]), f2bf(Wl[kk+3][n]));
      ushort4 hi = make_ushort4(f2bf(Wl[kk+4][n]), f2bf(Wl[kk+5][n]),
                                f2bf(Wl[kk+6][n]), f2bf(Wl[kk+7][n]));
      *(ushort4*)(dst + ((long)n << 7) + (p << 3)) = lo;
      *(ushort4*)(dst + ((long)n << 7) + (p << 3) + 4) = hi;
    }
  }
}

// ---------------- gaussian feature table bf16 [TBL_P][128] zero-padded ----
__global__ void k_ea_build(unsigned short* __restrict__ EA)
{
  int p = blockIdx.x;
  int g = threadIdx.x; // 128 threads
  float v = 0.f;
  if (g < NG_GAUSS) {
    float step = 10.0f / 49.0f;
    float off = g * step;
    float coeff = -0.5f / (step * step);
    float t = p * TBL_DT - off;
    v = __expf(coeff * t * t);
  }
  EA[p * 128 + g] = f2bf(v);
}

// ---------------- h init: h = emb[z] (fp32 + bf16 copy) -------------------
__global__ __launch_bounds__(256) void k_h_init(
    const float4* __restrict__ emb4, const int* __restrict__ z,
    float4* __restrict__ h4, ushort4* __restrict__ hb4, int N)
{
  int idx = blockIdx.x * 256 + threadIdx.x;
  if (idx >= N * 32) return;
  int n = idx >> 5, c = idx & 31;
  float4 v = emb4[z[n] * 32 + c];
  h4[idx] = v;
  hb4[idx] = make_ushort4(f2bf(v.x), f2bf(v.y), f2bf(v.z), f2bf(v.w));
}

// ---------------- fused GEMM chain (BM=32 tile, 2x2 wave layout) ----------
// Stage A (if Wa): tmp = ssp(X@Wa + ba)            (X bf16 [M][128])
// Stage B:         v = tmp@Wb + bb; [ssp]; [+R]; [*C(row*dscale)]; -> out1?
// Stage C (if Wc): out2 = v_bf16@Wc + bc  (bf16)
//   head mode (hw2!=0): per-row ssp(acc+bc)*hw2 -> reduce -> atomicAdd(outp)
// Weights pre-transposed/swizzled bf16 [128][128]. Batched over blockIdx.y.
__global__ __launch_bounds__(256) void k_fused(
    const unsigned short* __restrict__ X, long xstr,
    const unsigned short* __restrict__ Wa, long wastr,
    const float* __restrict__ ba, long bastr,
    const unsigned short* __restrict__ Wb, long wbstr,
    const float* __restrict__ bb, long bbstr,
    const float* __restrict__ R,
    void* __restrict__ out1, long o1str, int o1_bf16, int actB, int mulC,
    float dscale,
    const unsigned short* __restrict__ Wc, const float* __restrict__ bc,
    unsigned short* __restrict__ out2,
    const float* __restrict__ hw2, const float* __restrict__ hb2,
    const int* __restrict__ batchp, float* __restrict__ outp,
    int M)
{
  __shared__ unsigned short Xs[32][128];
  __shared__ unsigned short U[128][128];
  __shared__ unsigned short V[128][128];

  const int l = blockIdx.y;
  const int m0 = blockIdx.x * 32;
  const int tid = threadIdx.x;
  const unsigned short* Xb = X + (long)l * xstr;

  // stage X tile (bf16 16B chunks, XOR swizzle on chunk index)
  for (int idx = tid; idx < 512; idx += 256) {
    int r = idx >> 4, c = idx & 15;
    int m = m0 + r;
    int4 v = make_int4(0, 0, 0, 0);
    if (m < M) v = *(const int4*)(Xb + (long)m * 128 + c * 8);
    *(int4*)&Xs[r][(c ^ (r & 7)) << 3] = v;
  }
  if (Wa) {
    const int4* s = (const int4*)(Wa + (long)l * wastr);
    int4* d = (int4*)U;
    for (int i = tid; i < 2048; i += 256) d[i] = s[i];
  }
  {
    const int4* s = (const int4*)(Wb + (long)l * wbstr);
    int4* d = (int4*)V;
    for (int i = tid; i < 2048; i += 256) d[i] = s[i];
  }
  __syncthreads();

  const int wv = tid >> 6, lane = tid & 63;
  const int wr = wv >> 1, wc = wv & 1;
  const int lr = lane & 15, lk = lane >> 4;
  const int arow = (wr << 4) | lr;

  f32x4 acc[4];
  auto zacc = [&]() {
#pragma unroll
    for (int i = 0; i < 4; ++i)
#pragma unroll
      for (int j = 0; j < 4; ++j) acc[i][j] = 0.f;
  };
  auto gemm = [&](const unsigned short* Wl) {
#pragma unroll
    for (int kc = 0; kc < 4; ++kc) {
      int q = (kc << 2) | lk;
      bf16x8 a = *(const bf16x8*)&Xs[arow][(q ^ (arow & 7)) << 3];
#pragma unroll
      for (int nt = 0; nt < 4; ++nt) {
        int n = (wc << 6) | (nt << 4) | lr;
        bf16x8 b = *(const bf16x8*)(Wl + n * 128 + ((q ^ (n & 7)) << 3));
        acc[nt] = __builtin_amdgcn_mfma_f32_16x16x32_bf16(a, b, acc[nt], 0, 0, 0);
      }
    }
  };

  if (Wa) {
    const float* bab = ba + (long)l * bastr;
    zacc();
    gemm(&U[0][0]);
    __syncthreads();                   // all stage-A LDS reads done
#pragma unroll
    for (int nt = 0; nt < 4; ++nt) {
      int col = (wc << 6) | (nt << 4) | lr;
      float bv = bab[col];
#pragma unroll
      for (int r2 = 0; r2 < 4; ++r2) {
        int row = (wr << 4) | (lk << 2) | r2;
        float v2 = ssp_f(acc[nt][r2] + bv);
        int cch = col >> 3;
        Xs[row][((cch ^ (row & 7)) << 3) | (col & 7)] = f2bf(v2);
      }
    }
    if (Wc) {                          // refill U with Wc (read at stage C)
      const int4* s = (const int4*)Wc;
      int4* d = (int4*)U;
      for (int i = tid; i < 2048; i += 256) d[i] = s[i];
    }
    __syncthreads();
  }

  const float* bbb = bb + (long)l * bbstr;
  zacc();
  gemm(&V[0][0]);
  __syncthreads();                     // stage-B Xs reads done before overwrite

#pragma unroll
  for (int nt = 0; nt < 4; ++nt) {
    int col = (wc << 6) | (nt << 4) | lr;
    float bv = bbb[col];
#pragma unroll
    for (int r2 = 0; r2 < 4; ++r2) {
      int row = (wr << 4) | (lk << 2) | r2;
      int m = m0 + row;
      float v2 = acc[nt][r2] + bv;
      if (actB) v2 = ssp_f(v2);
      if (R && m < M) v2 += R[(long)m * 128 + col];
      if (mulC) {
        float d = (float)m * dscale;
        v2 *= 0.5f * (__cosf(d * (PI_F / 10.0f)) + 1.0f);
      }
      if (m < M && out1) {
        if (o1_bf16)
          ((unsigned short*)out1)[(long)l * o1str + (long)m * 128 + col] = f2bf(v2);
        else
          ((float*)out1)[(long)l * o1str + (long)m * 128 + col] = v2;
      }
      if (Wc) {
        int cch = col >> 3;
        Xs[row][((cch ^ (row & 7)) << 3) | (col & 7)] = f2bf(v2);
      }
    }
  }

  if (Wc) {
    __syncthreads();
    zacc();
    gemm(&U[0][0]);
    if (hw2) {
      // fused head: y = ssp(v@Wc + bc) . hw2 + hb2, segment-sum by batch.
      // head width = 64 -> entirely inside the wc==0 waves' columns.
      if (wc == 0) {
        float b1v[4], w2v[4];
#pragma unroll
        for (int nt = 0; nt < 4; ++nt) {
          int col = (nt << 4) | lr;
          b1v[nt] = bc[col];
          w2v[nt] = hw2[col];
        }
        float bias2 = hb2[0];
#pragma unroll
        for (int r2 = 0; r2 < 4; ++r2) {
          float sv = 0.f;
#pragma unroll
          for (int nt = 0; nt < 4; ++nt)
            sv += ssp_f(acc[nt][r2] + b1v[nt]) * w2v[nt];
          sv += __shfl_xor(sv, 1);
          sv += __shfl_xor(sv, 2);
          sv += __shfl_xor(sv, 4);
          sv += __shfl_xor(sv, 8);
          if (lr == 0) {
            int m = m0 + (wr << 4) + (lk << 2) + r2;
            if (m < M) atomicAdd(&outp[batchp[m]], sv + bias2);
          }
        }
      }
    } else {
#pragma unroll
      for (int nt = 0; nt < 4; ++nt) {
        int col = (wc << 6) | (nt << 4) | lr;
        float bv = bc[col];
#pragma unroll
        for (int r2 = 0; r2 < 4; ++r2) {
          int row = (wr << 4) | (lk << 2) | r2;
          int m = m0 + row;
          if (m < M)
            out2[(long)m * 128 + col] = f2bf(acc[nt][r2] + bv);
        }
      }
    }
  }
}

// ---------------- conv: per-node gather, scalar csr, 8-wide pipelined -----
__global__ __launch_bounds__(256) void k_conv(
    const int* __restrict__ csr, const int* __restrict__ ptr,
    const unsigned short* __restrict__ T, const unsigned short* __restrict__ hw,
    unsigned short* __restrict__ convb, int N)
{
  int wid = __builtin_amdgcn_readfirstlane((blockIdx.x * 256 + threadIdx.x) >> 6);
  int lane = threadIdx.x & 63;
  if (wid >= N) return;
  int s = __builtin_amdgcn_readfirstlane(ptr[wid]);
  int e = __builtin_amdgcn_readfirstlane(ptr[wid + 1]);
  const int la = lane << 1;
  float ax[8], ay[8];
#pragma unroll
  for (int i = 0; i < 8; ++i) { ax[i] = 0.f; ay[i] = 0.f; }
  int j = s;
  if (j + 8 <= e) {
    int cc[8];
#pragma unroll
    for (int i = 0; i < 8; ++i) cc[i] = __builtin_amdgcn_readfirstlane(csr[j + i]);
    for (; j + 16 <= e; j += 8) {
      unsigned tv[8], hv[8];
#pragma unroll
      for (int i = 0; i < 8; ++i) {
        unsigned pr = (unsigned)cc[i];
        tv[i] = *(const unsigned*)(T + ((size_t)(pr & 8191u) << 7) + la);
        hv[i] = *(const unsigned*)(hw + ((size_t)(pr >> 13) << 7) + la);
      }
#pragma unroll
      for (int i = 0; i < 8; ++i) cc[i] = __builtin_amdgcn_readfirstlane(csr[j + 8 + i]);
#pragma unroll
      for (int i = 0; i < 8; ++i) {
        float w0 = __uint_as_float(tv[i] << 16), w1 = __uint_as_float(tv[i] & 0xffff0000u);
        float h0 = __uint_as_float(hv[i] << 16), h1 = __uint_as_float(hv[i] & 0xffff0000u);
        ax[i] = fmaf(w0, h0, ax[i]); ay[i] = fmaf(w1, h1, ay[i]);
      }
    }
    {
      unsigned tv[8], hv[8];
#pragma unroll
      for (int i = 0; i < 8; ++i) {
        unsigned pr = (unsigned)cc[i];
        tv[i] = *(const unsigned*)(T + ((size_t)(pr & 8191u) << 7) + la);
        hv[i] = *(const unsigned*)(hw + ((size_t)(pr >> 13) << 7) + la);
      }
#pragma unroll
      for (int i = 0; i < 8; ++i) {
        float w0 = __uint_as_float(tv[i] << 16), w1 = __uint_as_float(tv[i] & 0xffff0000u);
        float h0 = __uint_as_float(hv[i] << 16), h1 = __uint_as_float(hv[i] & 0xffff0000u);
        ax[i] = fmaf(w0, h0, ax[i]); ay[i] = fmaf(w1, h1, ay[i]);
      }
    }
    j += 8;
  }
  for (; j < e; ++j) {
    unsigned pr = (unsigned)__builtin_amdgcn_readfirstlane(csr[j]);
    unsigned tv = *(const unsigned*)(T + ((size_t)(pr & 8191u) << 7) + la);
    unsigned hv = *(const unsigned*)(hw + ((size_t)(pr >> 13) << 7) + la);
    float w0 = __uint_as_float(tv << 16), w1 = __uint_as_float(tv & 0xffff0000u);
    float h0 = __uint_as_float(hv << 16), h1 = __uint_as_float(hv & 0xffff0000u);
    ax[0] = fmaf(w0, h0, ax[0]); ay[0] = fmaf(w1, h1, ay[0]);
  }
  float axs = ((ax[0] + ax[1]) + (ax[2] + ax[3])) + ((ax[4] + ax[5]) + (ax[6] + ax[7]));
  float ays = ((ay[0] + ay[1]) + (ay[2] + ay[3])) + ((ay[4] + ay[5]) + (ay[6] + ay[7]));
  unsigned outw = (unsigned)f2bf(axs) | ((unsigned)f2bf(ays) << 16);
  *(unsigned*)(convb + ((size_t)wid << 7) + la) = outw;
}

extern "C" void kernel_launch(void* const* d_in, const int* in_sizes, int n_in,
                              void* d_out, int out_size, void* d_ws, size_t ws_size,
                              hipStream_t stream) {
  (void)n_in; (void)ws_size;
  const float* pos     = (const float*)d_in[0];
  const int*   z       = (const int*)d_in[1];
  const int*   batch   = (const int*)d_in[2];
  const int*   ei      = (const int*)d_in[3];
  const float* emb     = (const float*)d_in[4];
  const float* mlp_w1  = (const float*)d_in[5];
  const float* mlp_b1  = (const float*)d_in[6];
  const float* mlp_w2  = (const float*)d_in[7];
  const float* mlp_b2  = (const float*)d_in[8];
  const float* aw_w    = (const float*)d_in[9];
  const float* aw_b    = (const float*)d_in[10];
  const float* out_w1  = (const float*)d_in[11];
  const float* out_b1  = (const float*)d_in[12];
  const float* out_w2  = (const float*)d_in[13];
  const float* out_b2  = (const float*)d_in[14];
  const float* head_w1 = (const float*)d_in[15];
  const float* head_b1 = (const float*)d_in[16];
  const float* head_w2 = (const float*)d_in[17];
  const float* head_b2 = (const float*)d_in[18];

  const int N  = in_sizes[0] / 3;
  const int E  = in_sizes[3] / 2;
  const int NG = out_size;
  const int L  = in_sizes[5] / (NG_GAUSS * HID);

  char* ws = (char*)d_ws;
  size_t off = 0;
  auto alloc = [&](size_t bytes) -> void* {
    off = (off + 255) & ~(size_t)255;
    void* p = ws + off;
    off += bytes;
    return p;
  };

  const size_t nh = (size_t)N * HID;
  float* h_buf = (float*)alloc(nh * 4 > (size_t)E * 4 ? nh * 4 : (size_t)E * 4);
  int*   epack = (int*)h_buf;                   // alias (disjoint lifetime)
  unsigned short* hb    = (unsigned short*)alloc(nh * 2);
  unsigned short* hw    = (unsigned short*)alloc(nh * 2);
  unsigned short* convb = (unsigned short*)alloc(
      nh * 2 > (size_t)TBL_P * 128 * 2 ? nh * 2 : (size_t)TBL_P * 128 * 2);
  unsigned short* EA    = convb;                // alias (EA used pre-conv)
  int* csr = (int*)alloc((size_t)E * 4);
  unsigned short* T   = (unsigned short*)alloc((size_t)L * TBL_P * 128 * 2);
  unsigned short* awt = (unsigned short*)alloc((size_t)L * 16384 * 2);
  unsigned short* o1t = (unsigned short*)alloc((size_t)L * 16384 * 2);
  unsigned short* o2t = (unsigned short*)alloc((size_t)L * 16384 * 2);
  unsigned short* m2t = (unsigned short*)alloc((size_t)L * 16384 * 2);
  unsigned short* m1t = (unsigned short*)alloc((size_t)L * 16384 * 2);
  unsigned short* hwt = (unsigned short*)alloc((size_t)16384 * 2);
  int* deg    = (int*)alloc((size_t)N * 4);
  int* ptr    = (int*)alloc((size_t)(N + 1) * 4);
  int* cursor = (int*)alloc((size_t)N * 4);

  hipMemsetAsync(deg, 0, (size_t)N * 4, stream);
  hipMemsetAsync(cursor, 0, (size_t)N * 4, stream);
  hipMemsetAsync(d_out, 0, (size_t)NG * 4, stream);

  int egrid = (E + 255) / 256;
  k_edge_pre<<<egrid, 256, 0, stream>>>(pos, ei, E, epack, deg);
  k_scan<<<1, 1024, 0, stream>>>(deg, ptr, N);
  k_csr_scatter<<<egrid, 256, 0, stream>>>(ei + E, epack, ptr, cursor, csr, E);

  k_wprep<<<dim3(L, 6), 256, 0, stream>>>(aw_w, out_w1, out_w2, mlp_w2, mlp_w1,
                                          head_w1, awt, o1t, o2t, m2t, m1t, hwt);
  k_ea_build<<<TBL_P, 128, 0, stream>>>(EA);

  // filter tables: T_l = ssp(ssp(EA@w1+b1)@w2+b2) * C(d), bf16, batched
  k_fused<<<dim3(TBL_P / 32, L), 256, 0, stream>>>(
      EA, 0L,
      m1t, 16384L, mlp_b1, 128L,
      m2t, 16384L, mlp_b2, 128L,
      (const float*)0,
      T, (long)TBL_P * 128, 1 /*bf16*/, 1 /*ssp*/, 1 /*mulC*/, TBL_DT,
      (const unsigned short*)0, (const float*)0, (unsigned short*)0,
      (const float*)0, (const float*)0, (const int*)0, (float*)0,
      TBL_P);

  k_h_init<<<(N * 32 + 255) / 256, 256, 0, stream>>>(
      (const float4*)emb, z, (float4*)h_buf, (ushort4*)hb, N);

  const int ngrid = (N + 31) / 32;
  const int wgrid = (N * 64 + 255) / 256;

  // initial hw = h0 @ aw_w[0] + aw_b[0]
  k_fused<<<dim3(ngrid, 1), 256, 0, stream>>>(
      hb, 0L,
      (const unsigned short*)0, 0L, (const float*)0, 0L,
      awt, 0L, aw_b, 0L,
      (const float*)0,
      hw, 0L, 1 /*bf16*/, 0, 0, 0.f,
      (const unsigned short*)0, (const float*)0, (unsigned short*)0,
      (const float*)0, (const float*)0, (const int*)0, (float*)0,
      N);

  for (int l = 0; l < L; ++l) {
    k_conv<<<wgrid, 256, 0, stream>>>(
        csr, ptr, T + (size_t)l * TBL_P * 128, hw, convb, N);
    const int last = (l + 1 == L);
    const unsigned short* Wc = last ? hwt : (awt + (size_t)(l + 1) * 16384);
    const float* bc = last ? head_b1 : (aw_b + (size_t)(l + 1) * 128);
    k_fused<<<dim3(ngrid, 1), 256, 0, stream>>>(
        convb, 0L,
        o1t + (size_t)l * 16384, 0L, out_b1 + (size_t)l * 128, 0L,
        o2t + (size_t)l * 16384, 0L, out_b2 + (size_t)l * 128, 0L,
        h_buf,
        last ? (void*)0 : (void*)h_buf, 0L, 0 /*fp32*/, 0 /*no act*/, 0, 0.f,
        Wc, bc, last ? (unsigned short*)0 : hw,
        last ? head_w2 : (const float*)0, last ? head_b2 : (const float*)0,
        last ? batch : (const int*)0, last ? (float*)d_out : (float*)0,
        N);
  }
}

// Round 7
// 497.168 us; speedup vs baseline: 3.3865x; 1.0195x over previous
//
#include <hip/hip_runtime.h>
#include <math.h>

#define HID 128
#define NG_GAUSS 50
#define TBL_P 8192
#define TBL_DMAX 12.8f
#define TBL_DT (TBL_DMAX / (float)TBL_P)
#define TBL_INV_DT ((float)TBL_P / TBL_DMAX)
#define PI_F 3.14159265358979323846f

typedef short bf16x8 __attribute__((ext_vector_type(8)));
typedef float f32x4 __attribute__((ext_vector_type(4)));

// fast shifted-softplus via HW transcendentals (v_exp_f32 / v_log_f32)
__device__ __forceinline__ float ssp_f(float x) {
  float e = __expf(-fabsf(x));
  return fmaxf(x, 0.f) + __logf(1.f + e) - 0.69314718055994530942f;
}
__device__ __forceinline__ unsigned short f2bf(float x) {
  unsigned u = __float_as_uint(x);
  unsigned r = (u + 0x7FFFu + ((u >> 16) & 1u)) >> 16;
  return (unsigned short)r;
}

// ---------------- edge precompute: pack (row<<13 | i0), degree histogram ---
__global__ __launch_bounds__(256) void k_edge_pre(
    const float* __restrict__ pos, const int* __restrict__ ei,
    int E, int* __restrict__ epack, int* __restrict__ deg)
{
  int e = blockIdx.x * 256 + threadIdx.x;
  if (e >= E) return;
  int r = ei[e];
  int c = ei[E + e];
  float dx = pos[3*r+0] - pos[3*c+0];
  float dy = pos[3*r+1] - pos[3*c+1];
  float dz = pos[3*r+2] - pos[3*c+2];
  float d = sqrtf(dx*dx + dy*dy + dz*dz);
  int i0 = (int)(d * TBL_INV_DT + 0.5f);   // nearest table row
  if (i0 > TBL_P - 1) i0 = TBL_P - 1;      // rows >= 12.8A give exactly 0
  epack[e] = (r << 13) | i0;
  atomicAdd(&deg[c], 1);
}

// ---------------- exclusive scan over degrees (single block, 2-level) -----
__global__ __launch_bounds__(1024) void k_scan(
    const int* __restrict__ deg, int* __restrict__ ptr, int N)
{
  __shared__ int wsum[16];
  int t = threadIdx.x;
  int chunk = (N + 1023) / 1024;
  int b = t * chunk;
  int e2 = min(b + chunk, N);
  int s = 0;
  for (int i = b; i < e2; ++i) s += deg[i];
  int lane = t & 63, w = t >> 6;
  int ps = s;
  for (int o = 1; o < 64; o <<= 1) { int x = __shfl_up(ps, o); if (lane >= o) ps += x; }
  if (lane == 63) wsum[w] = ps;
  __syncthreads();
  if (w == 0 && lane < 16) {
    int v = wsum[lane];
    int pv = v;
    for (int o = 1; o < 16; o <<= 1) { int x = __shfl_up(pv, o); if (lane >= o) pv += x; }
    wsum[lane] = pv - v;  // exclusive
  }
  __syncthreads();
  int base = wsum[w] + ps - s;
  for (int i = b; i < e2; ++i) { ptr[i] = base; base += deg[i]; }
  if (t == 1023) ptr[N] = base;
}

// ---------------- scatter edges into CSR order ----------------------------
__global__ __launch_bounds__(256) void k_csr_scatter(
    const int* __restrict__ col, const int* __restrict__ epack,
    const int* __restrict__ ptr, int* __restrict__ cursor,
    int* __restrict__ csr, int E)
{
  int e = blockIdx.x * 256 + threadIdx.x;
  if (e >= E) return;
  int c = col[e];
  int slot = ptr[c] + atomicAdd(&cursor[c], 1);
  csr[slot] = epack[e];
}

// ---------------- weight prep: bf16, transposed [n][k], chunk-XOR swizzle -
__global__ __launch_bounds__(256) void k_wprep(
    const float* __restrict__ aw_w, const float* __restrict__ out_w1,
    const float* __restrict__ out_w2, const float* __restrict__ mlp_w2,
    const float* __restrict__ mlp_w1, const float* __restrict__ head_w1,
    unsigned short* __restrict__ awt, unsigned short* __restrict__ o1t,
    unsigned short* __restrict__ o2t, unsigned short* __restrict__ m2t,
    unsigned short* __restrict__ m1t, unsigned short* __restrict__ hwt)
{
  __shared__ float Wl[64][132];
  int l = blockIdx.x, t = blockIdx.y;
  const float* src; unsigned short* dst; int K; int NCOL = 128;
  switch (t) {
    case 0:  src = aw_w;   dst = awt; K = 128; break;
    case 1:  src = out_w1; dst = o1t; K = 128; break;
    case 2:  src = out_w2; dst = o2t; K = 128; break;
    case 3:  src = mlp_w2; dst = m2t; K = 128; break;
    case 4:  src = mlp_w1; dst = m1t; K = NG_GAUSS; break;
    default:
      if (l) return;
      src = head_w1; dst = hwt; K = 128; NCOL = 64; break;
  }
  src += (long)l * K * NCOL;
  dst += (long)l * 128 * 128;
  const int tid = threadIdx.x;
  for (int k0 = 0; k0 < 128; k0 += 64) {
    __syncthreads();
    for (int idx = tid; idx < 64 * 128; idx += 256) {
      int kk = idx >> 7, n = idx & 127;
      int k = k0 + kk;
      Wl[kk][n] = (k < K && n < NCOL) ? src[(long)k * NCOL + n] : 0.f;
    }
    __syncthreads();
    for (int idx = tid; idx < 128 * 8; idx += 256) {
      int n = idx >> 3, pl = idx & 7;
      int p = (k0 >> 3) + pl;          // stored chunk position
      int q = p ^ (n & 7);             // logical chunk (same 8-chunk half)
      int kk = (q << 3) - k0;
      ushort4 lo = make_ushort4(f2bf(Wl[kk+0][n]), f2bf(Wl[kk+1][n]),
                                f2bf(Wl[kk+2][n]), f2bf(Wl[kk+3][n]));
      ushort4 hi = make_ushort4(f2bf(Wl[kk+4][n]), f2bf(Wl[kk+5][n]),
                                f2bf(Wl[kk+6][n]), f2bf(Wl[kk+7][n]));
      *(ushort4*)(dst + ((long)n << 7) + (p << 3)) = lo;
      *(ushort4*)(dst + ((long)n << 7) + (p << 3) + 4) = hi;
    }
  }
}

// ---------------- gaussian feature table bf16 [TBL_P][128] zero-padded ----
__global__ void k_ea_build(unsigned short* __restrict__ EA)
{
  int p = blockIdx.x;
  int g = threadIdx.x; // 128 threads
  float v = 0.f;
  if (g < NG_GAUSS) {
    float step = 10.0f / 49.0f;
    float off = g * step;
    float coeff = -0.5f / (step * step);
    float t = p * TBL_DT - off;
    v = __expf(coeff * t * t);
  }
  EA[p * 128 + g] = f2bf(v);
}

// ---------------- h init: h = emb[z] (fp32 + bf16 copy) -------------------
__global__ __launch_bounds__(256) void k_h_init(
    const float4* __restrict__ emb4, const int* __restrict__ z,
    float4* __restrict__ h4, ushort4* __restrict__ hb4, int N)
{
  int idx = blockIdx.x * 256 + threadIdx.x;
  if (idx >= N * 32) return;
  int n = idx >> 5, c = idx & 31;
  float4 v = emb4[z[n] * 32 + c];
  h4[idx] = v;
  hb4[idx] = make_ushort4(f2bf(v.x), f2bf(v.y), f2bf(v.z), f2bf(v.w));
}

// ---------------- fused GEMM chain (BM=32, single 32KB weight buffer) -----
// Stage A (if Wa): tmp = ssp(X@Wa + ba)            (X bf16 [M][128])
// Stage B:         v = tmp@Wb + bb; [ssp]; [+R]; [*C(row*dscale)]; -> out1?
// Stage C (if Wc): out2 = v_bf16@Wc + bc  (bf16)
//   head mode (hw2!=0): per-row ssp(acc+bc)*hw2 -> reduce -> atomicAdd(outp)
// Weights pre-transposed/swizzled bf16 [128][128]. Batched over blockIdx.y.
// LDS = 8KB Xs + 32KB Wbuf = 40KB -> 4 blocks/CU.
__global__ __launch_bounds__(256) void k_fused(
    const unsigned short* __restrict__ X, long xstr,
    const unsigned short* __restrict__ Wa, long wastr,
    const float* __restrict__ ba, long bastr,
    const unsigned short* __restrict__ Wb, long wbstr,
    const float* __restrict__ bb, long bbstr,
    const float* __restrict__ R,
    void* __restrict__ out1, long o1str, int o1_bf16, int actB, int mulC,
    float dscale,
    const unsigned short* __restrict__ Wc, const float* __restrict__ bc,
    unsigned short* __restrict__ out2,
    const float* __restrict__ hw2, const float* __restrict__ hb2,
    const int* __restrict__ batchp, float* __restrict__ outp,
    int M)
{
  __shared__ unsigned short Xs[32][128];
  __shared__ unsigned short Wbuf[128][128];

  const int l = blockIdx.y;
  const int m0 = blockIdx.x * 32;
  const int tid = threadIdx.x;
  const unsigned short* Xb = X + (long)l * xstr;

  // stage X tile (bf16 16B chunks, XOR swizzle on chunk index)
  for (int idx = tid; idx < 512; idx += 256) {
    int r = idx >> 4, c = idx & 15;
    int m = m0 + r;
    int4 v = make_int4(0, 0, 0, 0);
    if (m < M) v = *(const int4*)(Xb + (long)m * 128 + c * 8);
    *(int4*)&Xs[r][(c ^ (r & 7)) << 3] = v;
  }
  {
    const unsigned short* W0 = Wa ? (Wa + (long)l * wastr) : (Wb + (long)l * wbstr);
    const int4* s = (const int4*)W0;
    int4* d = (int4*)Wbuf;
    for (int i = tid; i < 2048; i += 256) d[i] = s[i];
  }
  __syncthreads();

  const int wv = tid >> 6, lane = tid & 63;
  const int wr = wv >> 1, wc = wv & 1;
  const int lr = lane & 15, lk = lane >> 4;
  const int arow = (wr << 4) | lr;

  f32x4 acc[4];
  auto zacc = [&]() {
#pragma unroll
    for (int i = 0; i < 4; ++i)
#pragma unroll
      for (int j = 0; j < 4; ++j) acc[i][j] = 0.f;
  };
  auto gemm = [&]() {
#pragma unroll
    for (int kc = 0; kc < 4; ++kc) {
      int q = (kc << 2) | lk;
      bf16x8 a = *(const bf16x8*)&Xs[arow][(q ^ (arow & 7)) << 3];
#pragma unroll
      for (int nt = 0; nt < 4; ++nt) {
        int n = (wc << 6) | (nt << 4) | lr;
        bf16x8 b = *(const bf16x8*)(&Wbuf[0][0] + n * 128 + ((q ^ (n & 7)) << 3));
        acc[nt] = __builtin_amdgcn_mfma_f32_16x16x32_bf16(a, b, acc[nt], 0, 0, 0);
      }
    }
  };

  if (Wa) {
    const float* bab = ba + (long)l * bastr;
    zacc();
    gemm();
    __syncthreads();                   // gemmA reads (Xs, Wbuf) done
#pragma unroll
    for (int nt = 0; nt < 4; ++nt) {
      int col = (wc << 6) | (nt << 4) | lr;
      float bv = bab[col];
#pragma unroll
      for (int r2 = 0; r2 < 4; ++r2) {
        int row = (wr << 4) | (lk << 2) | r2;
        float v2 = ssp_f(acc[nt][r2] + bv);
        int cch = col >> 3;
        Xs[row][((cch ^ (row & 7)) << 3) | (col & 7)] = f2bf(v2);
      }
    }
    {                                  // refill Wbuf with Wb
      const int4* s = (const int4*)(Wb + (long)l * wbstr);
      int4* d = (int4*)Wbuf;
      for (int i = tid; i < 2048; i += 256) d[i] = s[i];
    }
    __syncthreads();
  }

  const float* bbb = bb + (long)l * bbstr;
  zacc();
  gemm();                              // stage B
  __syncthreads();                     // gemmB reads (Xs, Wbuf) done

#pragma unroll
  for (int nt = 0; nt < 4; ++nt) {
    int col = (wc << 6) | (nt << 4) | lr;
    float bv = bbb[col];
#pragma unroll
    for (int r2 = 0; r2 < 4; ++r2) {
      int row = (wr << 4) | (lk << 2) | r2;
      int m = m0 + row;
      float v2 = acc[nt][r2] + bv;
      if (actB) v2 = ssp_f(v2);
      if (R && m < M) v2 += R[(long)m * 128 + col];
      if (mulC) {
        float d = (float)m * dscale;
        v2 *= 0.5f * (__cosf(d * (PI_F / 10.0f)) + 1.0f);
      }
      if (m < M && out1) {
        if (o1_bf16)
          ((unsigned short*)out1)[(long)l * o1str + (long)m * 128 + col] = f2bf(v2);
        else
          ((float*)out1)[(long)l * o1str + (long)m * 128 + col] = v2;
      }
      if (Wc) {
        int cch = col >> 3;
        Xs[row][((cch ^ (row & 7)) << 3) | (col & 7)] = f2bf(v2);
      }
    }
  }

  if (Wc) {
    {                                  // refill Wbuf with Wc
      const int4* s = (const int4*)Wc;
      int4* d = (int4*)Wbuf;
      for (int i = tid; i < 2048; i += 256) d[i] = s[i];
    }
    __syncthreads();
    zacc();
    gemm();
    if (hw2) {
      // fused head: y = ssp(v@Wc + bc) . hw2 + hb2, segment-sum by batch.
      // head width = 64 -> entirely inside the wc==0 waves' columns.
      if (wc == 0) {
        float b1v[4], w2v[4];
#pragma unroll
        for (int nt = 0; nt < 4; ++nt) {
          int col = (nt << 4) | lr;
          b1v[nt] = bc[col];
          w2v[nt] = hw2[col];
        }
        float bias2 = hb2[0];
#pragma unroll
        for (int r2 = 0; r2 < 4; ++r2) {
          float sv = 0.f;
#pragma unroll
          for (int nt = 0; nt < 4; ++nt)
            sv += ssp_f(acc[nt][r2] + b1v[nt]) * w2v[nt];
          sv += __shfl_xor(sv, 1);
          sv += __shfl_xor(sv, 2);
          sv += __shfl_xor(sv, 4);
          sv += __shfl_xor(sv, 8);
          if (lr == 0) {
            int m = m0 + (wr << 4) + (lk << 2) + r2;
            if (m < M) atomicAdd(&outp[batchp[m]], sv + bias2);
          }
        }
      }
    } else {
#pragma unroll
      for (int nt = 0; nt < 4; ++nt) {
        int col = (wc << 6) | (nt << 4) | lr;
        float bv = bc[col];
#pragma unroll
        for (int r2 = 0; r2 < 4; ++r2) {
          int row = (wr << 4) | (lk << 2) | r2;
          int m = m0 + row;
          if (m < M)
            out2[(long)m * 128 + col] = f2bf(acc[nt][r2] + bv);
        }
      }
    }
  }
}

// ---------------- conv: per-node gather, scalar csr, 8-wide pipelined -----
// hw loads are non-temporal (evict-first) so the 2MB T table stays L2-resident.
__global__ __launch_bounds__(256) void k_conv(
    const int* __restrict__ csr, const int* __restrict__ ptr,
    const unsigned short* __restrict__ T, const unsigned short* __restrict__ hw,
    unsigned short* __restrict__ convb, int N)
{
  int wid = __builtin_amdgcn_readfirstlane((blockIdx.x * 256 + threadIdx.x) >> 6);
  int lane = threadIdx.x & 63;
  if (wid >= N) return;
  int s = __builtin_amdgcn_readfirstlane(ptr[wid]);
  int e = __builtin_amdgcn_readfirstlane(ptr[wid + 1]);
  const int la = lane << 1;
  float ax[8], ay[8];
#pragma unroll
  for (int i = 0; i < 8; ++i) { ax[i] = 0.f; ay[i] = 0.f; }
  int j = s;
  if (j + 8 <= e) {
    int cc[8];
#pragma unroll
    for (int i = 0; i < 8; ++i) cc[i] = __builtin_amdgcn_readfirstlane(csr[j + i]);
    for (; j + 16 <= e; j += 8) {
      unsigned tv[8], hv[8];
#pragma unroll
      for (int i = 0; i < 8; ++i) {
        unsigned pr = (unsigned)cc[i];
        tv[i] = *(const unsigned*)(T + ((size_t)(pr & 8191u) << 7) + la);
        hv[i] = __builtin_nontemporal_load(
            (const unsigned*)(hw + ((size_t)(pr >> 13) << 7) + la));
      }
#pragma unroll
      for (int i = 0; i < 8; ++i) cc[i] = __builtin_amdgcn_readfirstlane(csr[j + 8 + i]);
#pragma unroll
      for (int i = 0; i < 8; ++i) {
        float w0 = __uint_as_float(tv[i] << 16), w1 = __uint_as_float(tv[i] & 0xffff0000u);
        float h0 = __uint_as_float(hv[i] << 16), h1 = __uint_as_float(hv[i] & 0xffff0000u);
        ax[i] = fmaf(w0, h0, ax[i]); ay[i] = fmaf(w1, h1, ay[i]);
      }
    }
    {
      unsigned tv[8], hv[8];
#pragma unroll
      for (int i = 0; i < 8; ++i) {
        unsigned pr = (unsigned)cc[i];
        tv[i] = *(const unsigned*)(T + ((size_t)(pr & 8191u) << 7) + la);
        hv[i] = __builtin_nontemporal_load(
            (const unsigned*)(hw + ((size_t)(pr >> 13) << 7) + la));
      }
#pragma unroll
      for (int i = 0; i < 8; ++i) {
        float w0 = __uint_as_float(tv[i] << 16), w1 = __uint_as_float(tv[i] & 0xffff0000u);
        float h0 = __uint_as_float(hv[i] << 16), h1 = __uint_as_float(hv[i] & 0xffff0000u);
        ax[i] = fmaf(w0, h0, ax[i]); ay[i] = fmaf(w1, h1, ay[i]);
      }
    }
    j += 8;
  }
  for (; j < e; ++j) {
    unsigned pr = (unsigned)__builtin_amdgcn_readfirstlane(csr[j]);
    unsigned tv = *(const unsigned*)(T + ((size_t)(pr & 8191u) << 7) + la);
    unsigned hv = __builtin_nontemporal_load(
        (const unsigned*)(hw + ((size_t)(pr >> 13) << 7) + la));
    float w0 = __uint_as_float(tv << 16), w1 = __uint_as_float(tv & 0xffff0000u);
    float h0 = __uint_as_float(hv << 16), h1 = __uint_as_float(hv & 0xffff0000u);
    ax[0] = fmaf(w0, h0, ax[0]); ay[0] = fmaf(w1, h1, ay[0]);
  }
  float axs = ((ax[0] + ax[1]) + (ax[2] + ax[3])) + ((ax[4] + ax[5]) + (ax[6] + ax[7]));
  float ays = ((ay[0] + ay[1]) + (ay[2] + ay[3])) + ((ay[4] + ay[5]) + (ay[6] + ay[7]));
  unsigned outw = (unsigned)f2bf(axs) | ((unsigned)f2bf(ays) << 16);
  *(unsigned*)(convb + ((size_t)wid << 7) + la) = outw;
}

extern "C" void kernel_launch(void* const* d_in, const int* in_sizes, int n_in,
                              void* d_out, int out_size, void* d_ws, size_t ws_size,
                              hipStream_t stream) {
  (void)n_in; (void)ws_size;
  const float* pos     = (const float*)d_in[0];
  const int*   z       = (const int*)d_in[1];
  const int*   batch   = (const int*)d_in[2];
  const int*   ei      = (const int*)d_in[3];
  const float* emb     = (const float*)d_in[4];
  const float* mlp_w1  = (const float*)d_in[5];
  const float* mlp_b1  = (const float*)d_in[6];
  const float* mlp_w2  = (const float*)d_in[7];
  const float* mlp_b2  = (const float*)d_in[8];
  const float* aw_w    = (const float*)d_in[9];
  const float* aw_b    = (const float*)d_in[10];
  const float* out_w1  = (const float*)d_in[11];
  const float* out_b1  = (const float*)d_in[12];
  const float* out_w2  = (const float*)d_in[13];
  const float* out_b2  = (const float*)d_in[14];
  const float* head_w1 = (const float*)d_in[15];
  const float* head_b1 = (const float*)d_in[16];
  const float* head_w2 = (const float*)d_in[17];
  const float* head_b2 = (const float*)d_in[18];

  const int N  = in_sizes[0] / 3;
  const int E  = in_sizes[3] / 2;
  const int NG = out_size;
  const int L  = in_sizes[5] / (NG_GAUSS * HID);

  char* ws = (char*)d_ws;
  size_t off = 0;
  auto alloc = [&](size_t bytes) -> void* {
    off = (off + 255) & ~(size_t)255;
    void* p = ws + off;
    off += bytes;
    return p;
  };

  const size_t nh = (size_t)N * HID;
  float* h_buf = (float*)alloc(nh * 4 > (size_t)E * 4 ? nh * 4 : (size_t)E * 4);
  int*   epack = (int*)h_buf;                   // alias (disjoint lifetime)
  unsigned short* hb    = (unsigned short*)alloc(nh * 2);
  unsigned short* hw    = (unsigned short*)alloc(nh * 2);
  unsigned short* convb = (unsigned short*)alloc(
      nh * 2 > (size_t)TBL_P * 128 * 2 ? nh * 2 : (size_t)TBL_P * 128 * 2);
  unsigned short* EA    = convb;                // alias (EA used pre-conv)
  int* csr = (int*)alloc((size_t)E * 4);
  unsigned short* T   = (unsigned short*)alloc((size_t)L * TBL_P * 128 * 2);
  unsigned short* awt = (unsigned short*)alloc((size_t)L * 16384 * 2);
  unsigned short* o1t = (unsigned short*)alloc((size_t)L * 16384 * 2);
  unsigned short* o2t = (unsigned short*)alloc((size_t)L * 16384 * 2);
  unsigned short* m2t = (unsigned short*)alloc((size_t)L * 16384 * 2);
  unsigned short* m1t = (unsigned short*)alloc((size_t)L * 16384 * 2);
  unsigned short* hwt = (unsigned short*)alloc((size_t)16384 * 2);
  int* deg    = (int*)alloc((size_t)N * 4);
  int* ptr    = (int*)alloc((size_t)(N + 1) * 4);
  int* cursor = (int*)alloc((size_t)N * 4);

  hipMemsetAsync(deg, 0, (size_t)N * 4, stream);
  hipMemsetAsync(cursor, 0, (size_t)N * 4, stream);
  hipMemsetAsync(d_out, 0, (size_t)NG * 4, stream);

  int egrid = (E + 255) / 256;
  k_edge_pre<<<egrid, 256, 0, stream>>>(pos, ei, E, epack, deg);
  k_scan<<<1, 1024, 0, stream>>>(deg, ptr, N);
  k_csr_scatter<<<egrid, 256, 0, stream>>>(ei + E, epack, ptr, cursor, csr, E);

  k_wprep<<<dim3(L, 6), 256, 0, stream>>>(aw_w, out_w1, out_w2, mlp_w2, mlp_w1,
                                          head_w1, awt, o1t, o2t, m2t, m1t, hwt);
  k_ea_build<<<TBL_P, 128, 0, stream>>>(EA);

  // filter tables: T_l = ssp(ssp(EA@w1+b1)@w2+b2) * C(d), bf16, batched
  k_fused<<<dim3(TBL_P / 32, L), 256, 0, stream>>>(
      EA, 0L,
      m1t, 16384L, mlp_b1, 128L,
      m2t, 16384L, mlp_b2, 128L,
      (const float*)0,
      T, (long)TBL_P * 128, 1 /*bf16*/, 1 /*ssp*/, 1 /*mulC*/, TBL_DT,
      (const unsigned short*)0, (const float*)0, (unsigned short*)0,
      (const float*)0, (const float*)0, (const int*)0, (float*)0,
      TBL_P);

  k_h_init<<<(N * 32 + 255) / 256, 256, 0, stream>>>(
      (const float4*)emb, z, (float4*)h_buf, (ushort4*)hb, N);

  const int ngrid = (N + 31) / 32;
  const int wgrid = (N * 64 + 255) / 256;

  // initial hw = h0 @ aw_w[0] + aw_b[0]
  k_fused<<<dim3(ngrid, 1), 256, 0, stream>>>(
      hb, 0L,
      (const unsigned short*)0, 0L, (const float*)0, 0L,
      awt, 0L, aw_b, 0L,
      (const float*)0,
      hw, 0L, 1 /*bf16*/, 0, 0, 0.f,
      (const unsigned short*)0, (const float*)0, (unsigned short*)0,
      (const float*)0, (const float*)0, (const int*)0, (float*)0,
      N);

  for (int l = 0; l < L; ++l) {
    k_conv<<<wgrid, 256, 0, stream>>>(
        csr, ptr, T + (size_t)l * TBL_P * 128, hw, convb, N);
    const int last = (l + 1 == L);
    const unsigned short* Wc = last ? hwt : (awt + (size_t)(l + 1) * 16384);
    const float* bc = last ? head_b1 : (aw_b + (size_t)(l + 1) * 128);
    k_fused<<<dim3(ngrid, 1), 256, 0, stream>>>(
        convb, 0L,
        o1t + (size_t)l * 16384, 0L, out_b1 + (size_t)l * 128, 0L,
        o2t + (size_t)l * 16384, 0L, out_b2 + (size_t)l * 128, 0L,
        h_buf,
        last ? (void*)0 : (void*)h_buf, 0L, 0 /*fp32*/, 0 /*no act*/, 0, 0.f,
        Wc, bc, last ? (unsigned short*)0 : hw,
        last ? head_w2 : (const float*)0, last ? head_b2 : (const float*)0,
        last ? batch : (const int*)0, last ? (float*)d_out : (float*)0,
        N);
  }
}